// Round 3
// baseline (3070.398 us; speedup 1.0000x reference)
//
#include <hip/hip_runtime.h>
#include <math.h>

#define N_NODES 50000
#define N_EDGES 800000
#define HID 128
#define LAT 64
#define IN_NODE 11
#define K_EDGE 261    // 2*HID + 1 + 4
#define KP1 288       // K_EDGE padded to multiple of 32
#define KN 256        // node MLP folded K (h + agg)
#define AST 296       // edge feature LDS row stride (bf16 elems), 288+8 pad
#define NST 264       // node feature LDS row stride, 256+8 pad
#define TST 136       // t1 LDS row stride, 128+8 pad

typedef __attribute__((ext_vector_type(8))) short short8;
typedef __attribute__((ext_vector_type(4))) short short4v;
typedef __attribute__((ext_vector_type(4))) float floatx4;

__device__ __forceinline__ float elu_f(float v) { return v > 0.0f ? v : expm1f(v); }

__device__ __forceinline__ short f2bf(float f) {
    unsigned int u = __builtin_bit_cast(unsigned int, f);
    u += 0x7fffu + ((u >> 16) & 1u);   // round-to-nearest-even
    return (short)(u >> 16);
}

// ---------------- radial: ||x[row]-x[col]||^2 per edge ----------------
__global__ void radial_kernel(const float* __restrict__ x, const int* __restrict__ edges,
                              float* __restrict__ radial) {
    int e = blockIdx.x * 256 + threadIdx.x;
    if (e >= N_EDGES) return;
    int r = edges[e], c = edges[N_EDGES + e];
    float dx = x[r*3+0] - x[c*3+0];
    float dy = x[r*3+1] - x[c*3+1];
    float dz = x[r*3+2] - x[c*3+2];
    radial[e] = dx*dx + dy*dy + dz*dz;
}

// ---------------- embedding: h = h0 @ emb_w + emb_b ----------------
__global__ void emb_kernel(const float* __restrict__ h0, const float* __restrict__ w,
                           const float* __restrict__ b, float* __restrict__ h) {
    int t = threadIdx.x;
    int n = blockIdx.x * 2 + (t >> 7);
    int c = t & 127;
    if (n >= N_NODES) return;
    float acc = b[c];
    #pragma unroll
    for (int k = 0; k < IN_NODE; ++k) acc += h0[n*IN_NODE + k] * w[k*HID + c];
    h[(size_t)n*HID + c] = acc;
}

// ---------------- weight prep: transpose + bf16 + pad/fold ----------------
__global__ void prep_weights(const float* __restrict__ ew1, const float* __restrict__ ew2,
                             const float* __restrict__ nw1, const float* __restrict__ nw2,
                             short* __restrict__ ew1T, short* __restrict__ ew2T,
                             short* __restrict__ nw1T, short* __restrict__ nw2T) {
    int idx = blockIdx.x * 256 + threadIdx.x;
    int stride = gridDim.x * 256;
    for (int i = idx; i < 2*128*KP1; i += stride) {
        int l = i / (128*KP1); int r = i % (128*KP1);
        int c = r / KP1; int k = r % KP1;
        float v = (k < K_EDGE) ? ew1[(size_t)l*K_EDGE*128 + (size_t)k*128 + c] : 0.0f;
        ew1T[i] = f2bf(v);
    }
    for (int i = idx; i < 2*128*128; i += stride) {
        int l = i / (128*128); int r = i % (128*128);
        int c = r / 128; int k = r % 128;
        ew2T[i] = f2bf(ew2[(size_t)l*128*128 + (size_t)k*128 + c]);
    }
    for (int i = idx; i < 2*128*KN; i += stride) {
        int l = i / (128*KN); int r = i % (128*KN);
        int c = r / KN; int k = r % KN;
        const float* base = nw1 + (size_t)l*384*128;
        float v = (k < 128) ? (base[(size_t)k*128 + c] + base[(size_t)(256+k)*128 + c])
                            : base[(size_t)k*128 + c];
        nw1T[i] = f2bf(v);
    }
    for (int i = idx; i < 2*128*128; i += stride) {
        int l = i / (128*128); int r = i % (128*128);
        int c = r / 128; int k = r % 128;
        nw2T[i] = f2bf(nw2[(size_t)l*128*128 + (size_t)k*128 + c]);
    }
}

// ---------------- MFMA edge MLP (2 layers) + atomic scatter ----------------
__global__ __launch_bounds__(256) void edge_mfma_kernel(
    const float* __restrict__ h, const float* __restrict__ radial,
    const float* __restrict__ edge_attr, const int* __restrict__ edges,
    const short* __restrict__ w1T, const float* __restrict__ b1,
    const short* __restrict__ w2T, const float* __restrict__ b2,
    float* __restrict__ agg)
{
    __shared__ short featA[32 * AST];   // 18944 B
    __shared__ short t1[32 * TST];      // 8704 B
    int t = threadIdx.x;
    int e0 = blockIdx.x * 32;

    // ---- stage gathered features as bf16, row-major [edge][k] ----
    {
        int el = t >> 3, j = t & 7;               // 8 threads per edge, 16 cols each
        int e = e0 + el;
        int r = edges[e], c = edges[N_EDGES + e];
        const float4* hr = (const float4*)(h + (size_t)r * HID) + j*4;
        const float4* hc = (const float4*)(h + (size_t)c * HID) + j*4;
        float4 v0 = hr[0], v1 = hr[1], v2 = hr[2], v3 = hr[3];
        float4 u0 = hc[0], u1 = hc[1], u2 = hc[2], u3 = hc[3];
        short8 s0 = { f2bf(v0.x), f2bf(v0.y), f2bf(v0.z), f2bf(v0.w),
                      f2bf(v1.x), f2bf(v1.y), f2bf(v1.z), f2bf(v1.w) };
        short8 s1 = { f2bf(v2.x), f2bf(v2.y), f2bf(v2.z), f2bf(v2.w),
                      f2bf(v3.x), f2bf(v3.y), f2bf(v3.z), f2bf(v3.w) };
        short8 s2 = { f2bf(u0.x), f2bf(u0.y), f2bf(u0.z), f2bf(u0.w),
                      f2bf(u1.x), f2bf(u1.y), f2bf(u1.z), f2bf(u1.w) };
        short8 s3 = { f2bf(u2.x), f2bf(u2.y), f2bf(u2.z), f2bf(u2.w),
                      f2bf(u3.x), f2bf(u3.y), f2bf(u3.z), f2bf(u3.w) };
        *(short8*)&featA[el*AST + j*16]       = s0;
        *(short8*)&featA[el*AST + j*16 + 8]   = s1;
        *(short8*)&featA[el*AST + 128 + j*16]     = s2;
        *(short8*)&featA[el*AST + 128 + j*16 + 8] = s3;
    }
    if (t < 32) {  // tail: radial, edge_attr, zero pad to 288
        int e = e0 + t;
        float4 ea = *(const float4*)(edge_attr + (size_t)e*4);
        short8 s = { f2bf(radial[e]), f2bf(ea.x), f2bf(ea.y), f2bf(ea.z), f2bf(ea.w),
                     0, 0, 0 };
        short8 z = {0,0,0,0,0,0,0,0};
        *(short8*)&featA[t*AST + 256] = s;
        *(short8*)&featA[t*AST + 264] = z;
        *(short8*)&featA[t*AST + 272] = z;
        *(short8*)&featA[t*AST + 280] = z;
    }
    __syncthreads();

    int lane = t & 63;
    int wv = t >> 6;          // wave: channel block c in [wv*32, wv*32+32)
    int l15 = lane & 15;
    int quad = lane >> 4;

    int r0 = edges[e0 + l15];
    int r1 = edges[e0 + 16 + l15];

    floatx4 acc[2][2] = {{{0,0,0,0},{0,0,0,0}},{{0,0,0,0},{0,0,0,0}}};

    // ---- layer 1: K = 288 ----
    #pragma unroll
    for (int ks = 0; ks < KP1/32; ++ks) {
        int koff = ks*32 + quad*8;
        short8 a0 = *(const short8*)&w1T[(size_t)(wv*32 + l15)*KP1 + koff];
        short8 a1 = *(const short8*)&w1T[(size_t)(wv*32 + 16 + l15)*KP1 + koff];
        short8 bb0 = *(const short8*)&featA[l15*AST + koff];
        short8 bb1 = *(const short8*)&featA[(16 + l15)*AST + koff];
        acc[0][0] = __builtin_amdgcn_mfma_f32_16x16x32_bf16(a0, bb0, acc[0][0], 0, 0, 0);
        acc[0][1] = __builtin_amdgcn_mfma_f32_16x16x32_bf16(a0, bb1, acc[0][1], 0, 0, 0);
        acc[1][0] = __builtin_amdgcn_mfma_f32_16x16x32_bf16(a1, bb0, acc[1][0], 0, 0, 0);
        acc[1][1] = __builtin_amdgcn_mfma_f32_16x16x32_bf16(a1, bb1, acc[1][1], 0, 0, 0);
    }

    // ---- epilogue 1: bias + elu, pack 4 channels -> 8B LDS write t1[e][c] ----
    #pragma unroll
    for (int mi = 0; mi < 2; ++mi) {
        int cb = wv*32 + mi*16 + quad*4;
        float g0 = b1[cb], g1 = b1[cb+1], g2 = b1[cb+2], g3 = b1[cb+3];
        #pragma unroll
        for (int ni = 0; ni < 2; ++ni) {
            short4v s = { f2bf(elu_f(acc[mi][ni][0] + g0)),
                          f2bf(elu_f(acc[mi][ni][1] + g1)),
                          f2bf(elu_f(acc[mi][ni][2] + g2)),
                          f2bf(elu_f(acc[mi][ni][3] + g3)) };
            *(short4v*)&t1[(ni*16 + l15)*TST + cb] = s;
        }
    }
    __syncthreads();

    floatx4 acc2[2][2] = {{{0,0,0,0},{0,0,0,0}},{{0,0,0,0},{0,0,0,0}}};

    // ---- layer 2: K = 128 ----
    #pragma unroll
    for (int ks = 0; ks < 4; ++ks) {
        int koff = ks*32 + quad*8;
        short8 a0 = *(const short8*)&w2T[(size_t)(wv*32 + l15)*128 + koff];
        short8 a1 = *(const short8*)&w2T[(size_t)(wv*32 + 16 + l15)*128 + koff];
        short8 bb0 = *(const short8*)&t1[l15*TST + koff];
        short8 bb1 = *(const short8*)&t1[(16 + l15)*TST + koff];
        acc2[0][0] = __builtin_amdgcn_mfma_f32_16x16x32_bf16(a0, bb0, acc2[0][0], 0, 0, 0);
        acc2[0][1] = __builtin_amdgcn_mfma_f32_16x16x32_bf16(a0, bb1, acc2[0][1], 0, 0, 0);
        acc2[1][0] = __builtin_amdgcn_mfma_f32_16x16x32_bf16(a1, bb0, acc2[1][0], 0, 0, 0);
        acc2[1][1] = __builtin_amdgcn_mfma_f32_16x16x32_bf16(a1, bb1, acc2[1][1], 0, 0, 0);
    }

    // ---- epilogue 2: bias + elu + HW atomic scatter-add to agg[row] ----
    #pragma unroll
    for (int mi = 0; mi < 2; ++mi) {
        int cb = wv*32 + mi*16 + quad*4;
        float g0 = b2[cb], g1 = b2[cb+1], g2 = b2[cb+2], g3 = b2[cb+3];
        #pragma unroll
        for (int ni = 0; ni < 2; ++ni) {
            int row = ni ? r1 : r0;
            float* dst = agg + (size_t)row * HID + cb;
            unsafeAtomicAdd(dst + 0, elu_f(acc2[mi][ni][0] + g0));
            unsafeAtomicAdd(dst + 1, elu_f(acc2[mi][ni][1] + g1));
            unsafeAtomicAdd(dst + 2, elu_f(acc2[mi][ni][2] + g2));
            unsafeAtomicAdd(dst + 3, elu_f(acc2[mi][ni][3] + g3));
        }
    }
}

// ---------------- MFMA node MLP (2 layers), in-place h update ----------------
__global__ __launch_bounds__(256) void node_mfma_kernel(
    const float* __restrict__ h, const float* __restrict__ agg,
    const short* __restrict__ w1T, const float* __restrict__ b1,
    const short* __restrict__ w2T, const float* __restrict__ b2,
    float* __restrict__ hout)
{
    __shared__ short featN[32 * NST];   // 16896 B
    __shared__ short t1[32 * TST];      // 8704 B
    int t = threadIdx.x;
    int n0 = blockIdx.x * 32;

    {
        int nl = t >> 3, j = t & 7;
        int n = n0 + nl;
        int idx = n < N_NODES ? n : N_NODES - 1;
        const float4* hp = (const float4*)(h   + (size_t)idx * HID) + j*4;
        const float4* ap = (const float4*)(agg + (size_t)idx * HID) + j*4;
        float4 v0 = hp[0], v1 = hp[1], v2 = hp[2], v3 = hp[3];
        float4 u0 = ap[0], u1 = ap[1], u2 = ap[2], u3 = ap[3];
        short8 s0 = { f2bf(v0.x), f2bf(v0.y), f2bf(v0.z), f2bf(v0.w),
                      f2bf(v1.x), f2bf(v1.y), f2bf(v1.z), f2bf(v1.w) };
        short8 s1 = { f2bf(v2.x), f2bf(v2.y), f2bf(v2.z), f2bf(v2.w),
                      f2bf(v3.x), f2bf(v3.y), f2bf(v3.z), f2bf(v3.w) };
        short8 s2 = { f2bf(u0.x), f2bf(u0.y), f2bf(u0.z), f2bf(u0.w),
                      f2bf(u1.x), f2bf(u1.y), f2bf(u1.z), f2bf(u1.w) };
        short8 s3 = { f2bf(u2.x), f2bf(u2.y), f2bf(u2.z), f2bf(u2.w),
                      f2bf(u3.x), f2bf(u3.y), f2bf(u3.z), f2bf(u3.w) };
        *(short8*)&featN[nl*NST + j*16]       = s0;
        *(short8*)&featN[nl*NST + j*16 + 8]   = s1;
        *(short8*)&featN[nl*NST + 128 + j*16]     = s2;
        *(short8*)&featN[nl*NST + 128 + j*16 + 8] = s3;
    }
    __syncthreads();

    int lane = t & 63;
    int wv = t >> 6;
    int l15 = lane & 15;
    int quad = lane >> 4;

    floatx4 acc[2][2] = {{{0,0,0,0},{0,0,0,0}},{{0,0,0,0},{0,0,0,0}}};

    #pragma unroll
    for (int ks = 0; ks < KN/32; ++ks) {
        int koff = ks*32 + quad*8;
        short8 a0 = *(const short8*)&w1T[(size_t)(wv*32 + l15)*KN + koff];
        short8 a1 = *(const short8*)&w1T[(size_t)(wv*32 + 16 + l15)*KN + koff];
        short8 bb0 = *(const short8*)&featN[l15*NST + koff];
        short8 bb1 = *(const short8*)&featN[(16 + l15)*NST + koff];
        acc[0][0] = __builtin_amdgcn_mfma_f32_16x16x32_bf16(a0, bb0, acc[0][0], 0, 0, 0);
        acc[0][1] = __builtin_amdgcn_mfma_f32_16x16x32_bf16(a0, bb1, acc[0][1], 0, 0, 0);
        acc[1][0] = __builtin_amdgcn_mfma_f32_16x16x32_bf16(a1, bb0, acc[1][0], 0, 0, 0);
        acc[1][1] = __builtin_amdgcn_mfma_f32_16x16x32_bf16(a1, bb1, acc[1][1], 0, 0, 0);
    }

    #pragma unroll
    for (int mi = 0; mi < 2; ++mi) {
        int cb = wv*32 + mi*16 + quad*4;
        float g0 = b1[cb], g1 = b1[cb+1], g2 = b1[cb+2], g3 = b1[cb+3];
        #pragma unroll
        for (int ni = 0; ni < 2; ++ni) {
            short4v s = { f2bf(elu_f(acc[mi][ni][0] + g0)),
                          f2bf(elu_f(acc[mi][ni][1] + g1)),
                          f2bf(elu_f(acc[mi][ni][2] + g2)),
                          f2bf(elu_f(acc[mi][ni][3] + g3)) };
            *(short4v*)&t1[(ni*16 + l15)*TST + cb] = s;
        }
    }
    __syncthreads();

    floatx4 acc2[2][2] = {{{0,0,0,0},{0,0,0,0}},{{0,0,0,0},{0,0,0,0}}};

    #pragma unroll
    for (int ks = 0; ks < 4; ++ks) {
        int koff = ks*32 + quad*8;
        short8 a0 = *(const short8*)&w2T[(size_t)(wv*32 + l15)*128 + koff];
        short8 a1 = *(const short8*)&w2T[(size_t)(wv*32 + 16 + l15)*128 + koff];
        short8 bb0 = *(const short8*)&t1[l15*TST + koff];
        short8 bb1 = *(const short8*)&t1[(16 + l15)*TST + koff];
        acc2[0][0] = __builtin_amdgcn_mfma_f32_16x16x32_bf16(a0, bb0, acc2[0][0], 0, 0, 0);
        acc2[0][1] = __builtin_amdgcn_mfma_f32_16x16x32_bf16(a0, bb1, acc2[0][1], 0, 0, 0);
        acc2[1][0] = __builtin_amdgcn_mfma_f32_16x16x32_bf16(a1, bb0, acc2[1][0], 0, 0, 0);
        acc2[1][1] = __builtin_amdgcn_mfma_f32_16x16x32_bf16(a1, bb1, acc2[1][1], 0, 0, 0);
    }

    #pragma unroll
    for (int mi = 0; mi < 2; ++mi) {
        int cb = wv*32 + mi*16 + quad*4;
        float g0 = b2[cb], g1 = b2[cb+1], g2 = b2[cb+2], g3 = b2[cb+3];
        #pragma unroll
        for (int ni = 0; ni < 2; ++ni) {
            int n = n0 + ni*16 + l15;
            if (n < N_NODES) {
                float4 v = { acc2[mi][ni][0] + g0, acc2[mi][ni][1] + g1,
                             acc2[mi][ni][2] + g2, acc2[mi][ni][3] + g3 };
                *(float4*)&hout[(size_t)n*HID + cb] = v;   // no activation on layer out
            }
        }
    }
}

// ---------------- output head: z = mu + 0.01*eps*exp(0.5*logvar) ----------------
__global__ void out_kernel(const float* __restrict__ h, const float* __restrict__ label,
                           const float* __restrict__ eps,
                           const float* __restrict__ mu_w, const float* __restrict__ mu_b,
                           const float* __restrict__ var_w, const float* __restrict__ var_b,
                           float* __restrict__ z)
{
    int t = threadIdx.x;
    int n = blockIdx.x * 4 + (t >> 6);
    int c = t & 63;
    if (n >= N_NODES) return;
    float am = mu_b[c], av = var_b[c];
    #pragma unroll 4
    for (int k = 0; k < HID; ++k) {
        float hv = h[(size_t)n*HID + k];
        am += hv * mu_w[k*LAT + c];
        av += hv * var_w[k*LAT + c];
    }
    #pragma unroll
    for (int k = 0; k < 7; ++k) {
        float lv = label[(size_t)n*7 + k];
        am += lv * mu_w[(HID+k)*LAT + c];
        av += lv * var_w[(HID+k)*LAT + c];
    }
    float sd = expf(av * 0.5f);
    z[(size_t)n*LAT + c] = am + 0.01f * eps[(size_t)n*LAT + c] * sd;
}

extern "C" void kernel_launch(void* const* d_in, const int* in_sizes, int n_in,
                              void* d_out, int out_size, void* d_ws, size_t ws_size,
                              hipStream_t stream) {
    const float* h0        = (const float*)d_in[0];
    const float* label     = (const float*)d_in[1];
    const float* x         = (const float*)d_in[2];
    const float* edge_attr = (const float*)d_in[3];
    const float* eps       = (const float*)d_in[4];
    const float* emb_w     = (const float*)d_in[5];
    const float* emb_b     = (const float*)d_in[6];
    const float* edge_w1   = (const float*)d_in[7];
    const float* edge_b1   = (const float*)d_in[8];
    const float* edge_w2   = (const float*)d_in[9];
    const float* edge_b2   = (const float*)d_in[10];
    const float* node_w1   = (const float*)d_in[11];
    const float* node_b1   = (const float*)d_in[12];
    const float* node_w2   = (const float*)d_in[13];
    const float* node_b2   = (const float*)d_in[14];
    const float* mu_w      = (const float*)d_in[15];
    const float* mu_b      = (const float*)d_in[16];
    const float* var_w     = (const float*)d_in[17];
    const float* var_b     = (const float*)d_in[18];
    const int*   edges     = (const int*)d_in[19];
    float* out = (float*)d_out;

    float* hA     = (float*)d_ws;                  // N*128 f32
    float* agg    = hA + (size_t)N_NODES * HID;    // N*128 f32
    float* radial = agg + (size_t)N_NODES * HID;   // E f32
    short* ew1T   = (short*)(radial + N_EDGES);    // 2*128*288
    short* ew2T   = ew1T + 2*128*KP1;              // 2*128*128
    short* nw1T   = ew2T + 2*128*128;              // 2*128*256
    short* nw2T   = nw1T + 2*128*KN;               // 2*128*128

    prep_weights<<<200, 256, 0, stream>>>(edge_w1, edge_w2, node_w1, node_w2,
                                          ew1T, ew2T, nw1T, nw2T);
    radial_kernel<<<(N_EDGES + 255) / 256, 256, 0, stream>>>(x, edges, radial);
    emb_kernel<<<N_NODES / 2, 256, 0, stream>>>(h0, emb_w, emb_b, hA);

    for (int l = 0; l < 2; ++l) {
        hipMemsetAsync(agg, 0, (size_t)N_NODES * HID * sizeof(float), stream);
        edge_mfma_kernel<<<N_EDGES / 32, 256, 0, stream>>>(
            hA, radial, edge_attr, edges,
            ew1T + (size_t)l * 128 * KP1, edge_b1 + l * HID,
            ew2T + (size_t)l * 128 * 128, edge_b2 + l * HID, agg);
        node_mfma_kernel<<<(N_NODES + 31) / 32, 256, 0, stream>>>(
            hA, agg,
            nw1T + (size_t)l * 128 * KN, node_b1 + l * HID,
            nw2T + (size_t)l * 128 * 128, node_b2 + l * HID, hA);
    }

    out_kernel<<<N_NODES / 4, 256, 0, stream>>>(hA, label, eps, mu_w, mu_b,
                                                var_w, var_b, out);
}

// Round 4
// 1132.561 us; speedup vs baseline: 2.7110x; 2.7110x over previous
//
#include <hip/hip_runtime.h>
#include <math.h>

#define N_NODES 50000
#define N_EDGES 800000
#define HID 128
#define LAT 64
#define IN_NODE 11
#define K_EDGE 261    // 2*HID + 1 + 4
#define KP1 288       // K_EDGE padded to multiple of 32
#define KN 256        // node MLP folded K (h + agg)
#define AST 296       // edge feature LDS row stride (bf16 elems), 288+8 pad
#define NST 264       // node feature LDS row stride, 256+8 pad
#define TST 136       // t1 LDS row stride, 128+8 pad
#define MST 132       // msg LDS row stride (floats), 128+4 pad
#define PCHUNK 196    // prefix-scan chunk: 256*196 >= 50000

typedef __attribute__((ext_vector_type(8))) short short8;
typedef __attribute__((ext_vector_type(4))) short short4v;
typedef __attribute__((ext_vector_type(4))) float floatx4;

__device__ __forceinline__ float elu_f(float v) { return v > 0.0f ? v : expm1f(v); }

__device__ __forceinline__ short f2bf(float f) {
    unsigned int u = __builtin_bit_cast(unsigned int, f);
    u += 0x7fffu + ((u >> 16) & 1u);   // round-to-nearest-even
    return (short)(u >> 16);
}

// ---------------- CSR build: count / prefix / scatter ----------------
__global__ void csr_count(const int* __restrict__ edges, int* __restrict__ cnt) {
    int e = blockIdx.x * 256 + threadIdx.x;
    if (e < N_EDGES) atomicAdd(&cnt[edges[e]], 1);
}

__global__ void csr_prefix(const int* __restrict__ cnt, int* __restrict__ cursor) {
    __shared__ int tot[256];
    __shared__ int pre[256];
    int t = threadIdx.x;
    int lo = t * PCHUNK, hi = lo + PCHUNK; if (hi > N_NODES) hi = N_NODES;
    int s = 0;
    for (int i = lo; i < hi; ++i) s += cnt[i];
    tot[t] = s;
    __syncthreads();
    if (t == 0) {
        int acc = 0;
        for (int i = 0; i < 256; ++i) { pre[i] = acc; acc += tot[i]; }
    }
    __syncthreads();
    int acc = pre[t];
    for (int i = lo; i < hi; ++i) { cursor[i] = acc; acc += cnt[i]; }
}

__global__ void csr_scatter(const int* __restrict__ edges, int* __restrict__ cursor,
                            int* __restrict__ perm) {
    int e = blockIdx.x * 256 + threadIdx.x;
    if (e < N_EDGES) {
        int pos = atomicAdd(&cursor[edges[e]], 1);
        perm[pos] = e;
    }
}

// ---------------- edge prep: materialize sorted-order edge data ----------------
__global__ void edge_prep(const int* __restrict__ edges, const int* __restrict__ perm,
                          const float* __restrict__ x, const float* __restrict__ edge_attr,
                          int* __restrict__ srow, int* __restrict__ scol,
                          float* __restrict__ radial_s, float* __restrict__ ea_s) {
    int i = blockIdx.x * 256 + threadIdx.x;
    if (i >= N_EDGES) return;
    int es = perm[i];
    int r = edges[es], c = edges[N_EDGES + es];
    srow[i] = r; scol[i] = c;
    float dx = x[r*3+0] - x[c*3+0];
    float dy = x[r*3+1] - x[c*3+1];
    float dz = x[r*3+2] - x[c*3+2];
    radial_s[i] = dx*dx + dy*dy + dz*dz;
    float4 ea = *(const float4*)(edge_attr + (size_t)es * 4);
    *(float4*)(ea_s + (size_t)i * 4) = ea;
}

// ---------------- embedding: h = h0 @ emb_w + emb_b ----------------
__global__ void emb_kernel(const float* __restrict__ h0, const float* __restrict__ w,
                           const float* __restrict__ b, float* __restrict__ h) {
    int t = threadIdx.x;
    int n = blockIdx.x * 2 + (t >> 7);
    int c = t & 127;
    if (n >= N_NODES) return;
    float acc = b[c];
    #pragma unroll
    for (int k = 0; k < IN_NODE; ++k) acc += h0[n*IN_NODE + k] * w[k*HID + c];
    h[(size_t)n*HID + c] = acc;
}

// ---------------- weight prep: transpose + bf16 + pad/fold ----------------
__global__ void prep_weights(const float* __restrict__ ew1, const float* __restrict__ ew2,
                             const float* __restrict__ nw1, const float* __restrict__ nw2,
                             short* __restrict__ ew1T, short* __restrict__ ew2T,
                             short* __restrict__ nw1T, short* __restrict__ nw2T) {
    int idx = blockIdx.x * 256 + threadIdx.x;
    int stride = gridDim.x * 256;
    for (int i = idx; i < 2*128*KP1; i += stride) {
        int l = i / (128*KP1); int r = i % (128*KP1);
        int c = r / KP1; int k = r % KP1;
        float v = (k < K_EDGE) ? ew1[(size_t)l*K_EDGE*128 + (size_t)k*128 + c] : 0.0f;
        ew1T[i] = f2bf(v);
    }
    for (int i = idx; i < 2*128*128; i += stride) {
        int l = i / (128*128); int r = i % (128*128);
        int c = r / 128; int k = r % 128;
        ew2T[i] = f2bf(ew2[(size_t)l*128*128 + (size_t)k*128 + c]);
    }
    for (int i = idx; i < 2*128*KN; i += stride) {
        int l = i / (128*KN); int r = i % (128*KN);
        int c = r / KN; int k = r % KN;
        const float* base = nw1 + (size_t)l*384*128;
        float v = (k < 128) ? (base[(size_t)k*128 + c] + base[(size_t)(256+k)*128 + c])
                            : base[(size_t)k*128 + c];
        nw1T[i] = f2bf(v);
    }
    for (int i = idx; i < 2*128*128; i += stride) {
        int l = i / (128*128); int r = i % (128*128);
        int c = r / 128; int k = r % 128;
        nw2T[i] = f2bf(nw2[(size_t)l*128*128 + (size_t)k*128 + c]);
    }
}

// ---------------- MFMA edge MLP (2 layers) + segmented LDS reduce ----------------
// Edges arrive sorted by destination row. Per block: 32 sorted edges.
// Messages land in LDS; a per-channel walk flushes one atomic per row-run.
__global__ __launch_bounds__(256) void edge_mfma_kernel(
    const float* __restrict__ h, const float* __restrict__ radial_s,
    const float* __restrict__ ea_s, const int* __restrict__ srow,
    const int* __restrict__ scol,
    const short* __restrict__ w1T, const float* __restrict__ b1,
    const short* __restrict__ w2T, const float* __restrict__ b2,
    float* __restrict__ agg)
{
    __shared__ __align__(16) short featA[32 * AST];   // 18944 B (reused as msgF)
    __shared__ __align__(16) short t1[32 * TST];      // 8704 B
    __shared__ int srowS[32];
    float* msgF = (float*)featA;                      // 32 x MST floats = 16896 B
    int t = threadIdx.x;
    int e0 = blockIdx.x * 32;

    // ---- stage gathered features as bf16, row-major [edge][k] ----
    {
        int el = t >> 3, j = t & 7;               // 8 threads per edge, 16 cols each
        int e = e0 + el;
        int r = srow[e], c = scol[e];
        if (j == 0) srowS[el] = r;
        const float4* hr = (const float4*)(h + (size_t)r * HID) + j*4;
        const float4* hc = (const float4*)(h + (size_t)c * HID) + j*4;
        float4 v0 = hr[0], v1 = hr[1], v2 = hr[2], v3 = hr[3];
        float4 u0 = hc[0], u1 = hc[1], u2 = hc[2], u3 = hc[3];
        short8 s0 = { f2bf(v0.x), f2bf(v0.y), f2bf(v0.z), f2bf(v0.w),
                      f2bf(v1.x), f2bf(v1.y), f2bf(v1.z), f2bf(v1.w) };
        short8 s1 = { f2bf(v2.x), f2bf(v2.y), f2bf(v2.z), f2bf(v2.w),
                      f2bf(v3.x), f2bf(v3.y), f2bf(v3.z), f2bf(v3.w) };
        short8 s2 = { f2bf(u0.x), f2bf(u0.y), f2bf(u0.z), f2bf(u0.w),
                      f2bf(u1.x), f2bf(u1.y), f2bf(u1.z), f2bf(u1.w) };
        short8 s3 = { f2bf(u2.x), f2bf(u2.y), f2bf(u2.z), f2bf(u2.w),
                      f2bf(u3.x), f2bf(u3.y), f2bf(u3.z), f2bf(u3.w) };
        *(short8*)&featA[el*AST + j*16]       = s0;
        *(short8*)&featA[el*AST + j*16 + 8]   = s1;
        *(short8*)&featA[el*AST + 128 + j*16]     = s2;
        *(short8*)&featA[el*AST + 128 + j*16 + 8] = s3;
    }
    if (t < 32) {  // tail: radial, edge_attr (sorted, coalesced), zero pad to 288
        int e = e0 + t;
        float4 ea = *(const float4*)(ea_s + (size_t)e*4);
        short8 s = { f2bf(radial_s[e]), f2bf(ea.x), f2bf(ea.y), f2bf(ea.z), f2bf(ea.w),
                     0, 0, 0 };
        short8 z = {0,0,0,0,0,0,0,0};
        *(short8*)&featA[t*AST + 256] = s;
        *(short8*)&featA[t*AST + 264] = z;
        *(short8*)&featA[t*AST + 272] = z;
        *(short8*)&featA[t*AST + 280] = z;
    }
    __syncthreads();

    int lane = t & 63;
    int wv = t >> 6;          // wave: channel block c in [wv*32, wv*32+32)
    int l15 = lane & 15;
    int quad = lane >> 4;

    floatx4 acc[2][2] = {{{0,0,0,0},{0,0,0,0}},{{0,0,0,0},{0,0,0,0}}};

    // ---- layer 1: K = 288 ----
    #pragma unroll
    for (int ks = 0; ks < KP1/32; ++ks) {
        int koff = ks*32 + quad*8;
        short8 a0 = *(const short8*)&w1T[(size_t)(wv*32 + l15)*KP1 + koff];
        short8 a1 = *(const short8*)&w1T[(size_t)(wv*32 + 16 + l15)*KP1 + koff];
        short8 bb0 = *(const short8*)&featA[l15*AST + koff];
        short8 bb1 = *(const short8*)&featA[(16 + l15)*AST + koff];
        acc[0][0] = __builtin_amdgcn_mfma_f32_16x16x32_bf16(a0, bb0, acc[0][0], 0, 0, 0);
        acc[0][1] = __builtin_amdgcn_mfma_f32_16x16x32_bf16(a0, bb1, acc[0][1], 0, 0, 0);
        acc[1][0] = __builtin_amdgcn_mfma_f32_16x16x32_bf16(a1, bb0, acc[1][0], 0, 0, 0);
        acc[1][1] = __builtin_amdgcn_mfma_f32_16x16x32_bf16(a1, bb1, acc[1][1], 0, 0, 0);
    }

    // ---- epilogue 1: bias + elu, pack 4 channels -> 8B LDS write t1[e][c] ----
    #pragma unroll
    for (int mi = 0; mi < 2; ++mi) {
        int cb = wv*32 + mi*16 + quad*4;
        float g0 = b1[cb], g1 = b1[cb+1], g2 = b1[cb+2], g3 = b1[cb+3];
        #pragma unroll
        for (int ni = 0; ni < 2; ++ni) {
            short4v s = { f2bf(elu_f(acc[mi][ni][0] + g0)),
                          f2bf(elu_f(acc[mi][ni][1] + g1)),
                          f2bf(elu_f(acc[mi][ni][2] + g2)),
                          f2bf(elu_f(acc[mi][ni][3] + g3)) };
            *(short4v*)&t1[(ni*16 + l15)*TST + cb] = s;
        }
    }
    __syncthreads();   // also: all featA reads done -> safe to overlay msgF after this

    floatx4 acc2[2][2] = {{{0,0,0,0},{0,0,0,0}},{{0,0,0,0},{0,0,0,0}}};

    // ---- layer 2: K = 128 ----
    #pragma unroll
    for (int ks = 0; ks < 4; ++ks) {
        int koff = ks*32 + quad*8;
        short8 a0 = *(const short8*)&w2T[(size_t)(wv*32 + l15)*128 + koff];
        short8 a1 = *(const short8*)&w2T[(size_t)(wv*32 + 16 + l15)*128 + koff];
        short8 bb0 = *(const short8*)&t1[l15*TST + koff];
        short8 bb1 = *(const short8*)&t1[(16 + l15)*TST + koff];
        acc2[0][0] = __builtin_amdgcn_mfma_f32_16x16x32_bf16(a0, bb0, acc2[0][0], 0, 0, 0);
        acc2[0][1] = __builtin_amdgcn_mfma_f32_16x16x32_bf16(a0, bb1, acc2[0][1], 0, 0, 0);
        acc2[1][0] = __builtin_amdgcn_mfma_f32_16x16x32_bf16(a1, bb0, acc2[1][0], 0, 0, 0);
        acc2[1][1] = __builtin_amdgcn_mfma_f32_16x16x32_bf16(a1, bb1, acc2[1][1], 0, 0, 0);
    }

    // ---- epilogue 2: bias + elu -> LDS message tile (f32) ----
    #pragma unroll
    for (int mi = 0; mi < 2; ++mi) {
        int cb = wv*32 + mi*16 + quad*4;
        float g0 = b2[cb], g1 = b2[cb+1], g2 = b2[cb+2], g3 = b2[cb+3];
        #pragma unroll
        for (int ni = 0; ni < 2; ++ni) {
            float4 v = { elu_f(acc2[mi][ni][0] + g0), elu_f(acc2[mi][ni][1] + g1),
                         elu_f(acc2[mi][ni][2] + g2), elu_f(acc2[mi][ni][3] + g3) };
            *(float4*)&msgF[(ni*16 + l15)*MST + cb] = v;
        }
    }
    __syncthreads();

    // ---- segmented reduce: thread (c, half) walks 16 sorted edges, flushes per run ----
    {
        int c = t & 127, half = t >> 7;
        int base = half * 16;
        int prow = srowS[base];
        float run = 0.0f;
        #pragma unroll
        for (int i = 0; i < 16; ++i) {
            int rr = srowS[base + i];
            if (rr != prow) {
                unsafeAtomicAdd(&agg[(size_t)prow * HID + c], run);
                run = 0.0f; prow = rr;
            }
            run += msgF[(base + i)*MST + c];
        }
        unsafeAtomicAdd(&agg[(size_t)prow * HID + c], run);
    }
}

// ---------------- MFMA node MLP (2 layers), in-place h update ----------------
__global__ __launch_bounds__(256) void node_mfma_kernel(
    const float* __restrict__ h, const float* __restrict__ agg,
    const short* __restrict__ w1T, const float* __restrict__ b1,
    const short* __restrict__ w2T, const float* __restrict__ b2,
    float* __restrict__ hout)
{
    __shared__ short featN[32 * NST];   // 16896 B
    __shared__ short t1[32 * TST];      // 8704 B
    int t = threadIdx.x;
    int n0 = blockIdx.x * 32;

    {
        int nl = t >> 3, j = t & 7;
        int n = n0 + nl;
        int idx = n < N_NODES ? n : N_NODES - 1;
        const float4* hp = (const float4*)(h   + (size_t)idx * HID) + j*4;
        const float4* ap = (const float4*)(agg + (size_t)idx * HID) + j*4;
        float4 v0 = hp[0], v1 = hp[1], v2 = hp[2], v3 = hp[3];
        float4 u0 = ap[0], u1 = ap[1], u2 = ap[2], u3 = ap[3];
        short8 s0 = { f2bf(v0.x), f2bf(v0.y), f2bf(v0.z), f2bf(v0.w),
                      f2bf(v1.x), f2bf(v1.y), f2bf(v1.z), f2bf(v1.w) };
        short8 s1 = { f2bf(v2.x), f2bf(v2.y), f2bf(v2.z), f2bf(v2.w),
                      f2bf(v3.x), f2bf(v3.y), f2bf(v3.z), f2bf(v3.w) };
        short8 s2 = { f2bf(u0.x), f2bf(u0.y), f2bf(u0.z), f2bf(u0.w),
                      f2bf(u1.x), f2bf(u1.y), f2bf(u1.z), f2bf(u1.w) };
        short8 s3 = { f2bf(u2.x), f2bf(u2.y), f2bf(u2.z), f2bf(u2.w),
                      f2bf(u3.x), f2bf(u3.y), f2bf(u3.z), f2bf(u3.w) };
        *(short8*)&featN[nl*NST + j*16]       = s0;
        *(short8*)&featN[nl*NST + j*16 + 8]   = s1;
        *(short8*)&featN[nl*NST + 128 + j*16]     = s2;
        *(short8*)&featN[nl*NST + 128 + j*16 + 8] = s3;
    }
    __syncthreads();

    int lane = t & 63;
    int wv = t >> 6;
    int l15 = lane & 15;
    int quad = lane >> 4;

    floatx4 acc[2][2] = {{{0,0,0,0},{0,0,0,0}},{{0,0,0,0},{0,0,0,0}}};

    #pragma unroll
    for (int ks = 0; ks < KN/32; ++ks) {
        int koff = ks*32 + quad*8;
        short8 a0 = *(const short8*)&w1T[(size_t)(wv*32 + l15)*KN + koff];
        short8 a1 = *(const short8*)&w1T[(size_t)(wv*32 + 16 + l15)*KN + koff];
        short8 bb0 = *(const short8*)&featN[l15*NST + koff];
        short8 bb1 = *(const short8*)&featN[(16 + l15)*NST + koff];
        acc[0][0] = __builtin_amdgcn_mfma_f32_16x16x32_bf16(a0, bb0, acc[0][0], 0, 0, 0);
        acc[0][1] = __builtin_amdgcn_mfma_f32_16x16x32_bf16(a0, bb1, acc[0][1], 0, 0, 0);
        acc[1][0] = __builtin_amdgcn_mfma_f32_16x16x32_bf16(a1, bb0, acc[1][0], 0, 0, 0);
        acc[1][1] = __builtin_amdgcn_mfma_f32_16x16x32_bf16(a1, bb1, acc[1][1], 0, 0, 0);
    }

    #pragma unroll
    for (int mi = 0; mi < 2; ++mi) {
        int cb = wv*32 + mi*16 + quad*4;
        float g0 = b1[cb], g1 = b1[cb+1], g2 = b1[cb+2], g3 = b1[cb+3];
        #pragma unroll
        for (int ni = 0; ni < 2; ++ni) {
            short4v s = { f2bf(elu_f(acc[mi][ni][0] + g0)),
                          f2bf(elu_f(acc[mi][ni][1] + g1)),
                          f2bf(elu_f(acc[mi][ni][2] + g2)),
                          f2bf(elu_f(acc[mi][ni][3] + g3)) };
            *(short4v*)&t1[(ni*16 + l15)*TST + cb] = s;
        }
    }
    __syncthreads();

    floatx4 acc2[2][2] = {{{0,0,0,0},{0,0,0,0}},{{0,0,0,0},{0,0,0,0}}};

    #pragma unroll
    for (int ks = 0; ks < 4; ++ks) {
        int koff = ks*32 + quad*8;
        short8 a0 = *(const short8*)&w2T[(size_t)(wv*32 + l15)*128 + koff];
        short8 a1 = *(const short8*)&w2T[(size_t)(wv*32 + 16 + l15)*128 + koff];
        short8 bb0 = *(const short8*)&t1[l15*TST + koff];
        short8 bb1 = *(const short8*)&t1[(16 + l15)*TST + koff];
        acc2[0][0] = __builtin_amdgcn_mfma_f32_16x16x32_bf16(a0, bb0, acc2[0][0], 0, 0, 0);
        acc2[0][1] = __builtin_amdgcn_mfma_f32_16x16x32_bf16(a0, bb1, acc2[0][1], 0, 0, 0);
        acc2[1][0] = __builtin_amdgcn_mfma_f32_16x16x32_bf16(a1, bb0, acc2[1][0], 0, 0, 0);
        acc2[1][1] = __builtin_amdgcn_mfma_f32_16x16x32_bf16(a1, bb1, acc2[1][1], 0, 0, 0);
    }

    #pragma unroll
    for (int mi = 0; mi < 2; ++mi) {
        int cb = wv*32 + mi*16 + quad*4;
        float g0 = b2[cb], g1 = b2[cb+1], g2 = b2[cb+2], g3 = b2[cb+3];
        #pragma unroll
        for (int ni = 0; ni < 2; ++ni) {
            int n = n0 + ni*16 + l15;
            if (n < N_NODES) {
                float4 v = { acc2[mi][ni][0] + g0, acc2[mi][ni][1] + g1,
                             acc2[mi][ni][2] + g2, acc2[mi][ni][3] + g3 };
                *(float4*)&hout[(size_t)n*HID + cb] = v;
            }
        }
    }
}

// ---------------- output head: z = mu + 0.01*eps*exp(0.5*logvar) ----------------
__global__ void out_kernel(const float* __restrict__ h, const float* __restrict__ label,
                           const float* __restrict__ eps,
                           const float* __restrict__ mu_w, const float* __restrict__ mu_b,
                           const float* __restrict__ var_w, const float* __restrict__ var_b,
                           float* __restrict__ z)
{
    int t = threadIdx.x;
    int n = blockIdx.x * 4 + (t >> 6);
    int c = t & 63;
    if (n >= N_NODES) return;
    float am = mu_b[c], av = var_b[c];
    #pragma unroll 4
    for (int k = 0; k < HID; ++k) {
        float hv = h[(size_t)n*HID + k];
        am += hv * mu_w[k*LAT + c];
        av += hv * var_w[k*LAT + c];
    }
    #pragma unroll
    for (int k = 0; k < 7; ++k) {
        float lv = label[(size_t)n*7 + k];
        am += lv * mu_w[(HID+k)*LAT + c];
        av += lv * var_w[(HID+k)*LAT + c];
    }
    float sd = expf(av * 0.5f);
    z[(size_t)n*LAT + c] = am + 0.01f * eps[(size_t)n*LAT + c] * sd;
}

extern "C" void kernel_launch(void* const* d_in, const int* in_sizes, int n_in,
                              void* d_out, int out_size, void* d_ws, size_t ws_size,
                              hipStream_t stream) {
    const float* h0        = (const float*)d_in[0];
    const float* label     = (const float*)d_in[1];
    const float* x         = (const float*)d_in[2];
    const float* edge_attr = (const float*)d_in[3];
    const float* eps       = (const float*)d_in[4];
    const float* emb_w     = (const float*)d_in[5];
    const float* emb_b     = (const float*)d_in[6];
    const float* edge_w1   = (const float*)d_in[7];
    const float* edge_b1   = (const float*)d_in[8];
    const float* edge_w2   = (const float*)d_in[9];
    const float* edge_b2   = (const float*)d_in[10];
    const float* node_w1   = (const float*)d_in[11];
    const float* node_b1   = (const float*)d_in[12];
    const float* node_w2   = (const float*)d_in[13];
    const float* node_b2   = (const float*)d_in[14];
    const float* mu_w      = (const float*)d_in[15];
    const float* mu_b      = (const float*)d_in[16];
    const float* var_w     = (const float*)d_in[17];
    const float* var_b     = (const float*)d_in[18];
    const int*   edges     = (const int*)d_in[19];
    float* out = (float*)d_out;

    float* hA       = (float*)d_ws;                    // N*128 f32
    float* agg      = hA + (size_t)N_NODES * HID;      // N*128 f32
    float* radial_s = agg + (size_t)N_NODES * HID;     // E f32
    float* ea_s     = radial_s + N_EDGES;              // E*4 f32
    int*   cnt      = (int*)(ea_s + (size_t)N_EDGES*4);// N int
    int*   cursor   = cnt + N_NODES;                   // N int
    int*   perm     = cursor + N_NODES;                // E int
    int*   srow     = perm + N_EDGES;                  // E int
    int*   scol     = srow + N_EDGES;                  // E int
    short* ew1T     = (short*)(scol + N_EDGES);        // 2*128*288
    short* ew2T     = ew1T + 2*128*KP1;                // 2*128*128
    short* nw1T     = ew2T + 2*128*128;                // 2*128*256
    short* nw2T     = nw1T + 2*128*KN;                 // 2*128*128

    // CSR build (once per launch, reused by both layers)
    hipMemsetAsync(cnt, 0, N_NODES * sizeof(int), stream);
    csr_count<<<(N_EDGES + 255) / 256, 256, 0, stream>>>(edges, cnt);
    csr_prefix<<<1, 256, 0, stream>>>(cnt, cursor);
    csr_scatter<<<(N_EDGES + 255) / 256, 256, 0, stream>>>(edges, cursor, perm);
    edge_prep<<<(N_EDGES + 255) / 256, 256, 0, stream>>>(edges, perm, x, edge_attr,
                                                         srow, scol, radial_s, ea_s);

    prep_weights<<<200, 256, 0, stream>>>(edge_w1, edge_w2, node_w1, node_w2,
                                          ew1T, ew2T, nw1T, nw2T);
    emb_kernel<<<N_NODES / 2, 256, 0, stream>>>(h0, emb_w, emb_b, hA);

    for (int l = 0; l < 2; ++l) {
        hipMemsetAsync(agg, 0, (size_t)N_NODES * HID * sizeof(float), stream);
        edge_mfma_kernel<<<N_EDGES / 32, 256, 0, stream>>>(
            hA, radial_s, ea_s, srow, scol,
            ew1T + (size_t)l * 128 * KP1, edge_b1 + l * HID,
            ew2T + (size_t)l * 128 * 128, edge_b2 + l * HID, agg);
        node_mfma_kernel<<<(N_NODES + 31) / 32, 256, 0, stream>>>(
            hA, agg,
            nw1T + (size_t)l * 128 * KN, node_b1 + l * HID,
            nw2T + (size_t)l * 128 * 128, node_b2 + l * HID, hA);
    }

    out_kernel<<<N_NODES / 4, 256, 0, stream>>>(hA, label, eps, mu_w, mu_b,
                                                var_w, var_b, out);
}

// Round 5
// 1025.841 us; speedup vs baseline: 2.9931x; 1.1040x over previous
//
#include <hip/hip_runtime.h>
#include <math.h>

#define N_NODES 50000
#define N_EDGES 800000
#define HID 128
#define LAT 64
#define IN_NODE 11
#define K_EDGE 261    // 2*HID + 1 + 4
#define KP1 288       // K_EDGE padded to multiple of 32
#define KN 256        // node MLP folded K (h + agg)
#define AST 296       // edge feature LDS row stride (bf16 elems), 288+8 pad
#define NST 264       // node feature LDS row stride, 256+8 pad
#define TST 136       // t1 LDS row stride, 128+8 pad
#define MST 132       // msg LDS row stride (floats), 128+4 pad
#define PCHUNK 196    // prefix-scan chunk: 256*196 >= 50000

typedef __attribute__((ext_vector_type(8))) short short8;
typedef __attribute__((ext_vector_type(4))) short short4v;
typedef __attribute__((ext_vector_type(4))) float floatx4;

__device__ __forceinline__ float elu_f(float v) { return v > 0.0f ? v : __expf(v) - 1.0f; }

__device__ __forceinline__ short f2bf(float f) {
    unsigned int u = __builtin_bit_cast(unsigned int, f);
    u += 0x7fffu + ((u >> 16) & 1u);   // round-to-nearest-even
    return (short)(u >> 16);
}

// ---------------- CSR build: count / prefix / scatter ----------------
__global__ void csr_count(const int* __restrict__ edges, int* __restrict__ cnt) {
    int e = blockIdx.x * 256 + threadIdx.x;
    if (e < N_EDGES) atomicAdd(&cnt[edges[e]], 1);
}

__global__ void csr_prefix(const int* __restrict__ cnt, int* __restrict__ cursor) {
    __shared__ int tot[256];
    __shared__ int pre[256];
    int t = threadIdx.x;
    int lo = t * PCHUNK, hi = lo + PCHUNK; if (hi > N_NODES) hi = N_NODES;
    int s = 0;
    for (int i = lo; i < hi; ++i) s += cnt[i];
    tot[t] = s;
    __syncthreads();
    if (t == 0) {
        int acc = 0;
        for (int i = 0; i < 256; ++i) { pre[i] = acc; acc += tot[i]; }
    }
    __syncthreads();
    int acc = pre[t];
    for (int i = lo; i < hi; ++i) { cursor[i] = acc; acc += cnt[i]; }
}

__global__ void csr_scatter(const int* __restrict__ edges, int* __restrict__ cursor,
                            int* __restrict__ perm) {
    int e = blockIdx.x * 256 + threadIdx.x;
    if (e < N_EDGES) {
        int pos = atomicAdd(&cursor[edges[e]], 1);
        perm[pos] = e;
    }
}

// ---------------- edge prep: sorted-order edge data, bf16 tail pack ----------------
__global__ void edge_prep(const int* __restrict__ edges, const int* __restrict__ perm,
                          const float* __restrict__ x, const float* __restrict__ edge_attr,
                          int* __restrict__ srow, int* __restrict__ scol,
                          short* __restrict__ tail_s) {
    int i = blockIdx.x * 256 + threadIdx.x;
    if (i >= N_EDGES) return;
    int es = perm[i];
    int r = edges[es], c = edges[N_EDGES + es];
    srow[i] = r; scol[i] = c;
    float dx = x[r*3+0] - x[c*3+0];
    float dy = x[r*3+1] - x[c*3+1];
    float dz = x[r*3+2] - x[c*3+2];
    float radial = dx*dx + dy*dy + dz*dz;
    float4 ea = *(const float4*)(edge_attr + (size_t)es * 4);
    short8 s = { f2bf(radial), f2bf(ea.x), f2bf(ea.y), f2bf(ea.z), f2bf(ea.w), 0, 0, 0 };
    *(short8*)(tail_s + (size_t)i * 8) = s;
}

// ---------------- embedding: h = h0 @ emb_w + emb_b (f32 + bf16 copies) ----------------
__global__ void emb_kernel(const float* __restrict__ h0, const float* __restrict__ w,
                           const float* __restrict__ b, float* __restrict__ h,
                           short* __restrict__ h_bf) {
    int t = threadIdx.x;
    int n = blockIdx.x * 2 + (t >> 7);
    int c = t & 127;
    if (n >= N_NODES) return;
    float acc = b[c];
    #pragma unroll
    for (int k = 0; k < IN_NODE; ++k) acc += h0[n*IN_NODE + k] * w[k*HID + c];
    h[(size_t)n*HID + c] = acc;
    h_bf[(size_t)n*HID + c] = f2bf(acc);
}

// ---------------- weight prep: transpose + bf16 + pad/fold ----------------
__global__ void prep_weights(const float* __restrict__ ew1, const float* __restrict__ ew2,
                             const float* __restrict__ nw1, const float* __restrict__ nw2,
                             short* __restrict__ ew1T, short* __restrict__ ew2T,
                             short* __restrict__ nw1T, short* __restrict__ nw2T) {
    int idx = blockIdx.x * 256 + threadIdx.x;
    int stride = gridDim.x * 256;
    for (int i = idx; i < 2*128*KP1; i += stride) {
        int l = i / (128*KP1); int r = i % (128*KP1);
        int c = r / KP1; int k = r % KP1;
        float v = (k < K_EDGE) ? ew1[(size_t)l*K_EDGE*128 + (size_t)k*128 + c] : 0.0f;
        ew1T[i] = f2bf(v);
    }
    for (int i = idx; i < 2*128*128; i += stride) {
        int l = i / (128*128); int r = i % (128*128);
        int c = r / 128; int k = r % 128;
        ew2T[i] = f2bf(ew2[(size_t)l*128*128 + (size_t)k*128 + c]);
    }
    for (int i = idx; i < 2*128*KN; i += stride) {
        int l = i / (128*KN); int r = i % (128*KN);
        int c = r / KN; int k = r % KN;
        const float* base = nw1 + (size_t)l*384*128;
        float v = (k < 128) ? (base[(size_t)k*128 + c] + base[(size_t)(256+k)*128 + c])
                            : base[(size_t)k*128 + c];
        nw1T[i] = f2bf(v);
    }
    for (int i = idx; i < 2*128*128; i += stride) {
        int l = i / (128*128); int r = i % (128*128);
        int c = r / 128; int k = r % 128;
        nw2T[i] = f2bf(nw2[(size_t)l*128*128 + (size_t)k*128 + c]);
    }
}

// ---------------- MFMA edge MLP (2 layers) + segmented LDS reduce ----------------
// Edges sorted by destination row; h pre-converted to bf16 -> staging is pure copy.
__global__ __launch_bounds__(256) void edge_mfma_kernel(
    const short* __restrict__ h_bf, const short* __restrict__ tail_s,
    const int* __restrict__ srow, const int* __restrict__ scol,
    const short* __restrict__ w1T, const float* __restrict__ b1,
    const short* __restrict__ w2T, const float* __restrict__ b2,
    float* __restrict__ agg)
{
    __shared__ __align__(16) short featA[32 * AST];   // 18944 B (reused as msgF)
    __shared__ __align__(16) short t1[32 * TST];      // 8704 B
    __shared__ int srowS[32];
    float* msgF = (float*)featA;                      // 32 x MST floats = 16896 B
    int t = threadIdx.x;
    int e0 = blockIdx.x * 32;

    // ---- stage gathered bf16 features, row-major [edge][k]: pure copies ----
    {
        int el = t >> 3, j = t & 7;               // 8 threads per edge, 16 cols each
        int e = e0 + el;
        int r = srow[e], c = scol[e];
        if (j == 0) srowS[el] = r;
        const short8* hr = (const short8*)(h_bf + (size_t)r * HID + j*16);
        const short8* hc = (const short8*)(h_bf + (size_t)c * HID + j*16);
        short8 s0 = hr[0], s1 = hr[1];
        short8 s2 = hc[0], s3 = hc[1];
        *(short8*)&featA[el*AST + j*16]       = s0;
        *(short8*)&featA[el*AST + j*16 + 8]   = s1;
        *(short8*)&featA[el*AST + 128 + j*16]     = s2;
        *(short8*)&featA[el*AST + 128 + j*16 + 8] = s3;
    }
    if (t < 32) {  // tail: pre-packed bf16 radial+edge_attr, zero pad to 288
        int e = e0 + t;
        short8 s = *(const short8*)(tail_s + (size_t)e * 8);
        short8 z = {0,0,0,0,0,0,0,0};
        *(short8*)&featA[t*AST + 256] = s;
        *(short8*)&featA[t*AST + 264] = z;
        *(short8*)&featA[t*AST + 272] = z;
        *(short8*)&featA[t*AST + 280] = z;
    }
    __syncthreads();

    int lane = t & 63;
    int wv = t >> 6;          // wave: channel block c in [wv*32, wv*32+32)
    int l15 = lane & 15;
    int quad = lane >> 4;

    floatx4 acc[2][2] = {{{0,0,0,0},{0,0,0,0}},{{0,0,0,0},{0,0,0,0}}};

    // ---- layer 1: K = 288 ----
    #pragma unroll
    for (int ks = 0; ks < KP1/32; ++ks) {
        int koff = ks*32 + quad*8;
        short8 a0 = *(const short8*)&w1T[(size_t)(wv*32 + l15)*KP1 + koff];
        short8 a1 = *(const short8*)&w1T[(size_t)(wv*32 + 16 + l15)*KP1 + koff];
        short8 bb0 = *(const short8*)&featA[l15*AST + koff];
        short8 bb1 = *(const short8*)&featA[(16 + l15)*AST + koff];
        acc[0][0] = __builtin_amdgcn_mfma_f32_16x16x32_bf16(a0, bb0, acc[0][0], 0, 0, 0);
        acc[0][1] = __builtin_amdgcn_mfma_f32_16x16x32_bf16(a0, bb1, acc[0][1], 0, 0, 0);
        acc[1][0] = __builtin_amdgcn_mfma_f32_16x16x32_bf16(a1, bb0, acc[1][0], 0, 0, 0);
        acc[1][1] = __builtin_amdgcn_mfma_f32_16x16x32_bf16(a1, bb1, acc[1][1], 0, 0, 0);
    }

    // ---- epilogue 1: bias + elu, pack 4 channels -> 8B LDS write t1[e][c] ----
    #pragma unroll
    for (int mi = 0; mi < 2; ++mi) {
        int cb = wv*32 + mi*16 + quad*4;
        float g0 = b1[cb], g1 = b1[cb+1], g2 = b1[cb+2], g3 = b1[cb+3];
        #pragma unroll
        for (int ni = 0; ni < 2; ++ni) {
            short4v s = { f2bf(elu_f(acc[mi][ni][0] + g0)),
                          f2bf(elu_f(acc[mi][ni][1] + g1)),
                          f2bf(elu_f(acc[mi][ni][2] + g2)),
                          f2bf(elu_f(acc[mi][ni][3] + g3)) };
            *(short4v*)&t1[(ni*16 + l15)*TST + cb] = s;
        }
    }
    __syncthreads();   // after this, featA reads done -> safe to overlay msgF

    floatx4 acc2[2][2] = {{{0,0,0,0},{0,0,0,0}},{{0,0,0,0},{0,0,0,0}}};

    // ---- layer 2: K = 128 ----
    #pragma unroll
    for (int ks = 0; ks < 4; ++ks) {
        int koff = ks*32 + quad*8;
        short8 a0 = *(const short8*)&w2T[(size_t)(wv*32 + l15)*128 + koff];
        short8 a1 = *(const short8*)&w2T[(size_t)(wv*32 + 16 + l15)*128 + koff];
        short8 bb0 = *(const short8*)&t1[l15*TST + koff];
        short8 bb1 = *(const short8*)&t1[(16 + l15)*TST + koff];
        acc2[0][0] = __builtin_amdgcn_mfma_f32_16x16x32_bf16(a0, bb0, acc2[0][0], 0, 0, 0);
        acc2[0][1] = __builtin_amdgcn_mfma_f32_16x16x32_bf16(a0, bb1, acc2[0][1], 0, 0, 0);
        acc2[1][0] = __builtin_amdgcn_mfma_f32_16x16x32_bf16(a1, bb0, acc2[1][0], 0, 0, 0);
        acc2[1][1] = __builtin_amdgcn_mfma_f32_16x16x32_bf16(a1, bb1, acc2[1][1], 0, 0, 0);
    }

    // ---- epilogue 2: bias + elu -> LDS message tile (f32) ----
    #pragma unroll
    for (int mi = 0; mi < 2; ++mi) {
        int cb = wv*32 + mi*16 + quad*4;
        float g0 = b2[cb], g1 = b2[cb+1], g2 = b2[cb+2], g3 = b2[cb+3];
        #pragma unroll
        for (int ni = 0; ni < 2; ++ni) {
            float4 v = { elu_f(acc2[mi][ni][0] + g0), elu_f(acc2[mi][ni][1] + g1),
                         elu_f(acc2[mi][ni][2] + g2), elu_f(acc2[mi][ni][3] + g3) };
            *(float4*)&msgF[(ni*16 + l15)*MST + cb] = v;
        }
    }
    __syncthreads();

    // ---- segmented reduce: thread (c, half) walks 16 sorted edges, flush per run ----
    {
        int c = t & 127, half = t >> 7;
        int base = half * 16;
        int prow = srowS[base];
        float run = 0.0f;
        #pragma unroll
        for (int i = 0; i < 16; ++i) {
            int rr = srowS[base + i];
            if (rr != prow) {
                unsafeAtomicAdd(&agg[(size_t)prow * HID + c], run);
                run = 0.0f; prow = rr;
            }
            run += msgF[(base + i)*MST + c];
        }
        unsafeAtomicAdd(&agg[(size_t)prow * HID + c], run);
    }
}

// ---------------- MFMA node MLP (2 layers), writes f32 + bf16 h ----------------
__global__ __launch_bounds__(256) void node_mfma_kernel(
    const short* __restrict__ h_bf, const float* __restrict__ agg,
    const short* __restrict__ w1T, const float* __restrict__ b1,
    const short* __restrict__ w2T, const float* __restrict__ b2,
    float* __restrict__ hout, short* __restrict__ hout_bf)
{
    __shared__ short featN[32 * NST];   // 16896 B
    __shared__ short t1[32 * TST];      // 8704 B
    int t = threadIdx.x;
    int n0 = blockIdx.x * 32;

    {
        int nl = t >> 3, j = t & 7;
        int n = n0 + nl;
        int idx = n < N_NODES ? n : N_NODES - 1;
        const short8* hp = (const short8*)(h_bf + (size_t)idx * HID + j*16);
        short8 s0 = hp[0], s1 = hp[1];
        const float4* ap = (const float4*)(agg + (size_t)idx * HID) + j*4;
        float4 u0 = ap[0], u1 = ap[1], u2 = ap[2], u3 = ap[3];
        short8 s2 = { f2bf(u0.x), f2bf(u0.y), f2bf(u0.z), f2bf(u0.w),
                      f2bf(u1.x), f2bf(u1.y), f2bf(u1.z), f2bf(u1.w) };
        short8 s3 = { f2bf(u2.x), f2bf(u2.y), f2bf(u2.z), f2bf(u2.w),
                      f2bf(u3.x), f2bf(u3.y), f2bf(u3.z), f2bf(u3.w) };
        *(short8*)&featN[nl*NST + j*16]       = s0;
        *(short8*)&featN[nl*NST + j*16 + 8]   = s1;
        *(short8*)&featN[nl*NST + 128 + j*16]     = s2;
        *(short8*)&featN[nl*NST + 128 + j*16 + 8] = s3;
    }
    __syncthreads();

    int lane = t & 63;
    int wv = t >> 6;
    int l15 = lane & 15;
    int quad = lane >> 4;

    floatx4 acc[2][2] = {{{0,0,0,0},{0,0,0,0}},{{0,0,0,0},{0,0,0,0}}};

    #pragma unroll
    for (int ks = 0; ks < KN/32; ++ks) {
        int koff = ks*32 + quad*8;
        short8 a0 = *(const short8*)&w1T[(size_t)(wv*32 + l15)*KN + koff];
        short8 a1 = *(const short8*)&w1T[(size_t)(wv*32 + 16 + l15)*KN + koff];
        short8 bb0 = *(const short8*)&featN[l15*NST + koff];
        short8 bb1 = *(const short8*)&featN[(16 + l15)*NST + koff];
        acc[0][0] = __builtin_amdgcn_mfma_f32_16x16x32_bf16(a0, bb0, acc[0][0], 0, 0, 0);
        acc[0][1] = __builtin_amdgcn_mfma_f32_16x16x32_bf16(a0, bb1, acc[0][1], 0, 0, 0);
        acc[1][0] = __builtin_amdgcn_mfma_f32_16x16x32_bf16(a1, bb0, acc[1][0], 0, 0, 0);
        acc[1][1] = __builtin_amdgcn_mfma_f32_16x16x32_bf16(a1, bb1, acc[1][1], 0, 0, 0);
    }

    #pragma unroll
    for (int mi = 0; mi < 2; ++mi) {
        int cb = wv*32 + mi*16 + quad*4;
        float g0 = b1[cb], g1 = b1[cb+1], g2 = b1[cb+2], g3 = b1[cb+3];
        #pragma unroll
        for (int ni = 0; ni < 2; ++ni) {
            short4v s = { f2bf(elu_f(acc[mi][ni][0] + g0)),
                          f2bf(elu_f(acc[mi][ni][1] + g1)),
                          f2bf(elu_f(acc[mi][ni][2] + g2)),
                          f2bf(elu_f(acc[mi][ni][3] + g3)) };
            *(short4v*)&t1[(ni*16 + l15)*TST + cb] = s;
        }
    }
    __syncthreads();

    floatx4 acc2[2][2] = {{{0,0,0,0},{0,0,0,0}},{{0,0,0,0},{0,0,0,0}}};

    #pragma unroll
    for (int ks = 0; ks < 4; ++ks) {
        int koff = ks*32 + quad*8;
        short8 a0 = *(const short8*)&w2T[(size_t)(wv*32 + l15)*128 + koff];
        short8 a1 = *(const short8*)&w2T[(size_t)(wv*32 + 16 + l15)*128 + koff];
        short8 bb0 = *(const short8*)&t1[l15*TST + koff];
        short8 bb1 = *(const short8*)&t1[(16 + l15)*TST + koff];
        acc2[0][0] = __builtin_amdgcn_mfma_f32_16x16x32_bf16(a0, bb0, acc2[0][0], 0, 0, 0);
        acc2[0][1] = __builtin_amdgcn_mfma_f32_16x16x32_bf16(a0, bb1, acc2[0][1], 0, 0, 0);
        acc2[1][0] = __builtin_amdgcn_mfma_f32_16x16x32_bf16(a1, bb0, acc2[1][0], 0, 0, 0);
        acc2[1][1] = __builtin_amdgcn_mfma_f32_16x16x32_bf16(a1, bb1, acc2[1][1], 0, 0, 0);
    }

    #pragma unroll
    for (int mi = 0; mi < 2; ++mi) {
        int cb = wv*32 + mi*16 + quad*4;
        float g0 = b2[cb], g1 = b2[cb+1], g2 = b2[cb+2], g3 = b2[cb+3];
        #pragma unroll
        for (int ni = 0; ni < 2; ++ni) {
            int n = n0 + ni*16 + l15;
            if (n < N_NODES) {
                float v0 = acc2[mi][ni][0] + g0, v1 = acc2[mi][ni][1] + g1;
                float v2 = acc2[mi][ni][2] + g2, v3 = acc2[mi][ni][3] + g3;
                float4 v = { v0, v1, v2, v3 };
                *(float4*)&hout[(size_t)n*HID + cb] = v;
                short4v s = { f2bf(v0), f2bf(v1), f2bf(v2), f2bf(v3) };
                *(short4v*)&hout_bf[(size_t)n*HID + cb] = s;
            }
        }
    }
}

// ---------------- output head: z = mu + 0.01*eps*exp(0.5*logvar) ----------------
__global__ void out_kernel(const float* __restrict__ h, const float* __restrict__ label,
                           const float* __restrict__ eps,
                           const float* __restrict__ mu_w, const float* __restrict__ mu_b,
                           const float* __restrict__ var_w, const float* __restrict__ var_b,
                           float* __restrict__ z)
{
    int t = threadIdx.x;
    int n = blockIdx.x * 4 + (t >> 6);
    int c = t & 63;
    if (n >= N_NODES) return;
    float am = mu_b[c], av = var_b[c];
    #pragma unroll 4
    for (int k = 0; k < HID; ++k) {
        float hv = h[(size_t)n*HID + k];
        am += hv * mu_w[k*LAT + c];
        av += hv * var_w[k*LAT + c];
    }
    #pragma unroll
    for (int k = 0; k < 7; ++k) {
        float lv = label[(size_t)n*7 + k];
        am += lv * mu_w[(HID+k)*LAT + c];
        av += lv * var_w[(HID+k)*LAT + c];
    }
    float sd = expf(av * 0.5f);
    z[(size_t)n*LAT + c] = am + 0.01f * eps[(size_t)n*LAT + c] * sd;
}

extern "C" void kernel_launch(void* const* d_in, const int* in_sizes, int n_in,
                              void* d_out, int out_size, void* d_ws, size_t ws_size,
                              hipStream_t stream) {
    const float* h0        = (const float*)d_in[0];
    const float* label     = (const float*)d_in[1];
    const float* x         = (const float*)d_in[2];
    const float* edge_attr = (const float*)d_in[3];
    const float* eps       = (const float*)d_in[4];
    const float* emb_w     = (const float*)d_in[5];
    const float* emb_b     = (const float*)d_in[6];
    const float* edge_w1   = (const float*)d_in[7];
    const float* edge_b1   = (const float*)d_in[8];
    const float* edge_w2   = (const float*)d_in[9];
    const float* edge_b2   = (const float*)d_in[10];
    const float* node_w1   = (const float*)d_in[11];
    const float* node_b1   = (const float*)d_in[12];
    const float* node_w2   = (const float*)d_in[13];
    const float* node_b2   = (const float*)d_in[14];
    const float* mu_w      = (const float*)d_in[15];
    const float* mu_b      = (const float*)d_in[16];
    const float* var_w     = (const float*)d_in[17];
    const float* var_b     = (const float*)d_in[18];
    const int*   edges     = (const int*)d_in[19];
    float* out = (float*)d_out;

    float* hA       = (float*)d_ws;                     // N*128 f32
    float* agg      = hA + (size_t)N_NODES * HID;       // N*128 f32
    short* h_bf     = (short*)(agg + (size_t)N_NODES * HID);  // N*128 bf16
    short* tail_s   = h_bf + (size_t)N_NODES * HID;     // E*8 bf16
    int*   cnt      = (int*)(tail_s + (size_t)N_EDGES * 8);   // N int
    int*   cursor   = cnt + N_NODES;                    // N int
    int*   perm     = cursor + N_NODES;                 // E int
    int*   srow     = perm + N_EDGES;                   // E int
    int*   scol     = srow + N_EDGES;                   // E int
    short* ew1T     = (short*)(scol + N_EDGES);         // 2*128*288
    short* ew2T     = ew1T + 2*128*KP1;                 // 2*128*128
    short* nw1T     = ew2T + 2*128*128;                 // 2*128*256
    short* nw2T     = nw1T + 2*128*KN;                  // 2*128*128

    // CSR build (once per launch, reused by both layers)
    hipMemsetAsync(cnt, 0, N_NODES * sizeof(int), stream);
    csr_count<<<(N_EDGES + 255) / 256, 256, 0, stream>>>(edges, cnt);
    csr_prefix<<<1, 256, 0, stream>>>(cnt, cursor);
    csr_scatter<<<(N_EDGES + 255) / 256, 256, 0, stream>>>(edges, cursor, perm);
    edge_prep<<<(N_EDGES + 255) / 256, 256, 0, stream>>>(edges, perm, x, edge_attr,
                                                         srow, scol, tail_s);

    prep_weights<<<200, 256, 0, stream>>>(edge_w1, edge_w2, node_w1, node_w2,
                                          ew1T, ew2T, nw1T, nw2T);
    emb_kernel<<<N_NODES / 2, 256, 0, stream>>>(h0, emb_w, emb_b, hA, h_bf);

    for (int l = 0; l < 2; ++l) {
        hipMemsetAsync(agg, 0, (size_t)N_NODES * HID * sizeof(float), stream);
        edge_mfma_kernel<<<N_EDGES / 32, 256, 0, stream>>>(
            h_bf, tail_s, srow, scol,
            ew1T + (size_t)l * 128 * KP1, edge_b1 + l * HID,
            ew2T + (size_t)l * 128 * 128, edge_b2 + l * HID, agg);
        node_mfma_kernel<<<(N_NODES + 31) / 32, 256, 0, stream>>>(
            h_bf, agg,
            nw1T + (size_t)l * 128 * KN, node_b1 + l * HID,
            nw2T + (size_t)l * 128 * 128, node_b2 + l * HID, hA, h_bf);
    }

    out_kernel<<<N_NODES / 4, 256, 0, stream>>>(hA, label, eps, mu_w, mu_b,
                                                var_w, var_b, out);
}

// Round 6
// 862.778 us; speedup vs baseline: 3.5587x; 1.1890x over previous
//
#include <hip/hip_runtime.h>
#include <math.h>

#define N_NODES 50000
#define N_EDGES 800000
#define HID 128
#define LAT 64
#define IN_NODE 11
#define K_EDGE 261    // 2*HID + 1 + 4
#define KP1 288       // K_EDGE padded to multiple of 32
#define KN 256        // node MLP folded K (h + agg)
#define AST 296       // edge feature LDS row stride (bf16 elems), 288+8 pad
#define NST 264       // node feature LDS row stride, 256+8 pad
#define TST 136       // t1 LDS row stride, 128+8 pad
#define MST 132       // msg LDS row stride (floats), 128+4 pad
#define PCHUNK 196    // prefix-scan chunk: 256*196 >= 50000
#define NTPB 20       // edge tiles per block (grid 1250)

typedef __attribute__((ext_vector_type(8))) short short8;
typedef __attribute__((ext_vector_type(4))) short short4v;
typedef __attribute__((ext_vector_type(4))) float floatx4;

__device__ __forceinline__ float elu_f(float v) { return v > 0.0f ? v : __expf(v) - 1.0f; }

__device__ __forceinline__ short f2bf(float f) {
    unsigned int u = __builtin_bit_cast(unsigned int, f);
    u += 0x7fffu + ((u >> 16) & 1u);   // round-to-nearest-even
    return (short)(u >> 16);
}

__device__ __forceinline__ float bf2f(short s) {
    unsigned int u = ((unsigned int)(unsigned short)s) << 16;
    return __builtin_bit_cast(float, u);
}

// ---------------- CSR pass 1: count + radial + bf16 tail pack (coalesced) ----------------
__global__ void csr_count_tail(const int* __restrict__ edges, const float* __restrict__ x,
                               const float* __restrict__ edge_attr,
                               int* __restrict__ cnt, short* __restrict__ tail_u) {
    int e = blockIdx.x * 256 + threadIdx.x;
    if (e >= N_EDGES) return;
    int r = edges[e], c = edges[N_EDGES + e];
    atomicAdd(&cnt[r], 1);
    float dx = x[r*3+0] - x[c*3+0];
    float dy = x[r*3+1] - x[c*3+1];
    float dz = x[r*3+2] - x[c*3+2];
    float radial = dx*dx + dy*dy + dz*dz;
    float4 ea = *(const float4*)(edge_attr + (size_t)e * 4);
    short8 s = { f2bf(radial), f2bf(ea.x), f2bf(ea.y), f2bf(ea.z), f2bf(ea.w), 0, 0, 0 };
    *(short8*)(tail_u + (size_t)e * 8) = s;
}

// ---------------- CSR pass 2: prefix over per-row counts ----------------
__global__ void csr_prefix(const int* __restrict__ cnt, int* __restrict__ cursor) {
    __shared__ int tot[256];
    __shared__ int pre[256];
    int t = threadIdx.x;
    int lo = t * PCHUNK, hi = lo + PCHUNK; if (hi > N_NODES) hi = N_NODES;
    int s = 0;
    for (int i = lo; i < hi; ++i) s += cnt[i];
    tot[t] = s;
    __syncthreads();
    if (t == 0) {
        int acc = 0;
        for (int i = 0; i < 256; ++i) { pre[i] = acc; acc += tot[i]; }
    }
    __syncthreads();
    int acc = pre[t];
    for (int i = lo; i < hi; ++i) { cursor[i] = acc; acc += cnt[i]; }
}

// ---------------- CSR pass 3: place srow/scol/tail in sorted order ----------------
__global__ void csr_place(const int* __restrict__ edges, const short* __restrict__ tail_u,
                          int* __restrict__ cursor, int* __restrict__ srow,
                          int* __restrict__ scol, short* __restrict__ tail_s) {
    int e = blockIdx.x * 256 + threadIdx.x;
    if (e >= N_EDGES) return;
    int r = edges[e], c = edges[N_EDGES + e];
    short8 s = *(const short8*)(tail_u + (size_t)e * 8);
    int pos = atomicAdd(&cursor[r], 1);
    srow[pos] = r; scol[pos] = c;
    *(short8*)(tail_s + (size_t)pos * 8) = s;
}

// ---------------- embedding: h_bf = bf16(h0 @ emb_w + emb_b) ----------------
__global__ void emb_kernel(const float* __restrict__ h0, const float* __restrict__ w,
                           const float* __restrict__ b, short* __restrict__ h_bf) {
    int t = threadIdx.x;
    int n = blockIdx.x * 2 + (t >> 7);
    int c = t & 127;
    if (n >= N_NODES) return;
    float acc = b[c];
    #pragma unroll
    for (int k = 0; k < IN_NODE; ++k) acc += h0[n*IN_NODE + k] * w[k*HID + c];
    h_bf[(size_t)n*HID + c] = f2bf(acc);
}

// ---------------- weight prep: transpose + bf16 + pad/fold ----------------
__global__ void prep_weights(const float* __restrict__ ew1, const float* __restrict__ ew2,
                             const float* __restrict__ nw1, const float* __restrict__ nw2,
                             short* __restrict__ ew1T, short* __restrict__ ew2T,
                             short* __restrict__ nw1T, short* __restrict__ nw2T) {
    int idx = blockIdx.x * 256 + threadIdx.x;
    int stride = gridDim.x * 256;
    for (int i = idx; i < 2*128*KP1; i += stride) {
        int l = i / (128*KP1); int r = i % (128*KP1);
        int c = r / KP1; int k = r % KP1;
        float v = (k < K_EDGE) ? ew1[(size_t)l*K_EDGE*128 + (size_t)k*128 + c] : 0.0f;
        ew1T[i] = f2bf(v);
    }
    for (int i = idx; i < 2*128*128; i += stride) {
        int l = i / (128*128); int r = i % (128*128);
        int c = r / 128; int k = r % 128;
        ew2T[i] = f2bf(ew2[(size_t)l*128*128 + (size_t)k*128 + c]);
    }
    for (int i = idx; i < 2*128*KN; i += stride) {
        int l = i / (128*KN); int r = i % (128*KN);
        int c = r / KN; int k = r % KN;
        const float* base = nw1 + (size_t)l*384*128;
        float v = (k < 128) ? (base[(size_t)k*128 + c] + base[(size_t)(256+k)*128 + c])
                            : base[(size_t)k*128 + c];
        nw1T[i] = f2bf(v);
    }
    for (int i = idx; i < 2*128*128; i += stride) {
        int l = i / (128*128); int r = i % (128*128);
        int c = r / 128; int k = r % 128;
        nw2T[i] = f2bf(nw2[(size_t)l*128*128 + (size_t)k*128 + c]);
    }
}

// ---------------- MFMA edge MLP: register-resident weights, NTPB tiles/block ----------------
__global__ __launch_bounds__(256, 2) void edge_mfma_kernel(
    const short* __restrict__ h_bf, const short* __restrict__ tail_s,
    const int* __restrict__ srow, const int* __restrict__ scol,
    const short* __restrict__ w1T, const float* __restrict__ b1,
    const short* __restrict__ w2T, const float* __restrict__ b2,
    float* __restrict__ agg)
{
    __shared__ __align__(16) short featA[32 * AST];   // 18944 B
    __shared__ __align__(16) short t1[32 * TST];      // 8704 B
    __shared__ __align__(16) float msgF[32 * MST];    // 16896 B
    __shared__ int srowS[32];
    int t = threadIdx.x;
    int lane = t & 63;
    int wv = t >> 6;          // wave: channel block [wv*32, wv*32+32)
    int l15 = lane & 15;
    int quad = lane >> 4;
    int el = t >> 3, j = t & 7;

    // ---- preload this wave's weight fragments into registers (once) ----
    short8 aw1[2][9], aw2[2][4];
    float4 b1v[2], b2v[2];
    #pragma unroll
    for (int mi = 0; mi < 2; ++mi) {
        #pragma unroll
        for (int ks = 0; ks < 9; ++ks)
            aw1[mi][ks] = *(const short8*)&w1T[(size_t)(wv*32 + mi*16 + l15)*KP1 + ks*32 + quad*8];
        #pragma unroll
        for (int ks = 0; ks < 4; ++ks)
            aw2[mi][ks] = *(const short8*)&w2T[(size_t)(wv*32 + mi*16 + l15)*128 + ks*32 + quad*8];
        b1v[mi] = *(const float4*)&b1[wv*32 + mi*16 + quad*4];
        b2v[mi] = *(const float4*)&b2[wv*32 + mi*16 + quad*4];
    }

    for (int it = 0; it < NTPB; ++it) {
        int e0 = (blockIdx.x * NTPB + it) * 32;
        __syncthreads();   // protect featA/srowS/msgF from previous iteration's readers

        // ---- stage 32 edges' gathered bf16 features ----
        {
            int e = e0 + el;
            int r = srow[e], c = scol[e];
            if (j == 0) srowS[el] = r;
            const short8* hr = (const short8*)(h_bf + (size_t)r * HID + j*16);
            const short8* hc = (const short8*)(h_bf + (size_t)c * HID + j*16);
            short8 s0 = hr[0], s1 = hr[1];
            short8 s2 = hc[0], s3 = hc[1];
            *(short8*)&featA[el*AST + j*16]       = s0;
            *(short8*)&featA[el*AST + j*16 + 8]   = s1;
            *(short8*)&featA[el*AST + 128 + j*16]     = s2;
            *(short8*)&featA[el*AST + 128 + j*16 + 8] = s3;
        }
        if (t < 32) {
            int e = e0 + t;
            short8 s = *(const short8*)(tail_s + (size_t)e * 8);
            short8 z = {0,0,0,0,0,0,0,0};
            *(short8*)&featA[t*AST + 256] = s;
            *(short8*)&featA[t*AST + 264] = z;
            *(short8*)&featA[t*AST + 272] = z;
            *(short8*)&featA[t*AST + 280] = z;
        }
        __syncthreads();

        // ---- layer 1: K = 288, A resident ----
        floatx4 acc[2][2] = {{{0,0,0,0},{0,0,0,0}},{{0,0,0,0},{0,0,0,0}}};
        #pragma unroll
        for (int ks = 0; ks < 9; ++ks) {
            int koff = ks*32 + quad*8;
            short8 bb0 = *(const short8*)&featA[l15*AST + koff];
            short8 bb1 = *(const short8*)&featA[(16 + l15)*AST + koff];
            acc[0][0] = __builtin_amdgcn_mfma_f32_16x16x32_bf16(aw1[0][ks], bb0, acc[0][0], 0, 0, 0);
            acc[0][1] = __builtin_amdgcn_mfma_f32_16x16x32_bf16(aw1[0][ks], bb1, acc[0][1], 0, 0, 0);
            acc[1][0] = __builtin_amdgcn_mfma_f32_16x16x32_bf16(aw1[1][ks], bb0, acc[1][0], 0, 0, 0);
            acc[1][1] = __builtin_amdgcn_mfma_f32_16x16x32_bf16(aw1[1][ks], bb1, acc[1][1], 0, 0, 0);
        }

        // ---- epilogue 1: bias + elu -> bf16 t1[e][c] ----
        #pragma unroll
        for (int mi = 0; mi < 2; ++mi) {
            int cb = wv*32 + mi*16 + quad*4;
            #pragma unroll
            for (int ni = 0; ni < 2; ++ni) {
                short4v s = { f2bf(elu_f(acc[mi][ni][0] + b1v[mi].x)),
                              f2bf(elu_f(acc[mi][ni][1] + b1v[mi].y)),
                              f2bf(elu_f(acc[mi][ni][2] + b1v[mi].z)),
                              f2bf(elu_f(acc[mi][ni][3] + b1v[mi].w)) };
                *(short4v*)&t1[(ni*16 + l15)*TST + cb] = s;
            }
        }
        __syncthreads();

        // ---- layer 2: K = 128, A resident ----
        floatx4 acc2[2][2] = {{{0,0,0,0},{0,0,0,0}},{{0,0,0,0},{0,0,0,0}}};
        #pragma unroll
        for (int ks = 0; ks < 4; ++ks) {
            int koff = ks*32 + quad*8;
            short8 bb0 = *(const short8*)&t1[l15*TST + koff];
            short8 bb1 = *(const short8*)&t1[(16 + l15)*TST + koff];
            acc2[0][0] = __builtin_amdgcn_mfma_f32_16x16x32_bf16(aw2[0][ks], bb0, acc2[0][0], 0, 0, 0);
            acc2[0][1] = __builtin_amdgcn_mfma_f32_16x16x32_bf16(aw2[0][ks], bb1, acc2[0][1], 0, 0, 0);
            acc2[1][0] = __builtin_amdgcn_mfma_f32_16x16x32_bf16(aw2[1][ks], bb0, acc2[1][0], 0, 0, 0);
            acc2[1][1] = __builtin_amdgcn_mfma_f32_16x16x32_bf16(aw2[1][ks], bb1, acc2[1][1], 0, 0, 0);
        }

        // ---- epilogue 2: bias + elu -> f32 msg tile ----
        #pragma unroll
        for (int mi = 0; mi < 2; ++mi) {
            int cb = wv*32 + mi*16 + quad*4;
            #pragma unroll
            for (int ni = 0; ni < 2; ++ni) {
                float4 v = { elu_f(acc2[mi][ni][0] + b2v[mi].x), elu_f(acc2[mi][ni][1] + b2v[mi].y),
                             elu_f(acc2[mi][ni][2] + b2v[mi].z), elu_f(acc2[mi][ni][3] + b2v[mi].w) };
                *(float4*)&msgF[(ni*16 + l15)*MST + cb] = v;
            }
        }
        __syncthreads();

        // ---- segmented reduce: thread (c, half) walks 16 sorted edges, flush per run ----
        {
            int c = t & 127, half = t >> 7;
            int base = half * 16;
            int prow = srowS[base];
            float run = 0.0f;
            #pragma unroll
            for (int i = 0; i < 16; ++i) {
                int rr = srowS[base + i];
                if (rr != prow) {
                    unsafeAtomicAdd(&agg[(size_t)prow * HID + c], run);
                    run = 0.0f; prow = rr;
                }
                run += msgF[(base + i)*MST + c];
            }
            unsafeAtomicAdd(&agg[(size_t)prow * HID + c], run);
        }
    }
}

// ---------------- MFMA node MLP (2 layers), bf16 h in/out ----------------
__global__ __launch_bounds__(256) void node_mfma_kernel(
    const short* __restrict__ h_bf, const float* __restrict__ agg,
    const short* __restrict__ w1T, const float* __restrict__ b1,
    const short* __restrict__ w2T, const float* __restrict__ b2,
    short* __restrict__ hout_bf)
{
    __shared__ short featN[32 * NST];   // 16896 B
    __shared__ short t1[32 * TST];      // 8704 B
    int t = threadIdx.x;
    int n0 = blockIdx.x * 32;

    {
        int nl = t >> 3, j = t & 7;
        int n = n0 + nl;
        int idx = n < N_NODES ? n : N_NODES - 1;
        const short8* hp = (const short8*)(h_bf + (size_t)idx * HID + j*16);
        short8 s0 = hp[0], s1 = hp[1];
        const float4* ap = (const float4*)(agg + (size_t)idx * HID) + j*4;
        float4 u0 = ap[0], u1 = ap[1], u2 = ap[2], u3 = ap[3];
        short8 s2 = { f2bf(u0.x), f2bf(u0.y), f2bf(u0.z), f2bf(u0.w),
                      f2bf(u1.x), f2bf(u1.y), f2bf(u1.z), f2bf(u1.w) };
        short8 s3 = { f2bf(u2.x), f2bf(u2.y), f2bf(u2.z), f2bf(u2.w),
                      f2bf(u3.x), f2bf(u3.y), f2bf(u3.z), f2bf(u3.w) };
        *(short8*)&featN[nl*NST + j*16]       = s0;
        *(short8*)&featN[nl*NST + j*16 + 8]   = s1;
        *(short8*)&featN[nl*NST + 128 + j*16]     = s2;
        *(short8*)&featN[nl*NST + 128 + j*16 + 8] = s3;
    }
    __syncthreads();

    int lane = t & 63;
    int wv = t >> 6;
    int l15 = lane & 15;
    int quad = lane >> 4;

    floatx4 acc[2][2] = {{{0,0,0,0},{0,0,0,0}},{{0,0,0,0},{0,0,0,0}}};

    #pragma unroll
    for (int ks = 0; ks < KN/32; ++ks) {
        int koff = ks*32 + quad*8;
        short8 a0 = *(const short8*)&w1T[(size_t)(wv*32 + l15)*KN + koff];
        short8 a1 = *(const short8*)&w1T[(size_t)(wv*32 + 16 + l15)*KN + koff];
        short8 bb0 = *(const short8*)&featN[l15*NST + koff];
        short8 bb1 = *(const short8*)&featN[(16 + l15)*NST + koff];
        acc[0][0] = __builtin_amdgcn_mfma_f32_16x16x32_bf16(a0, bb0, acc[0][0], 0, 0, 0);
        acc[0][1] = __builtin_amdgcn_mfma_f32_16x16x32_bf16(a0, bb1, acc[0][1], 0, 0, 0);
        acc[1][0] = __builtin_amdgcn_mfma_f32_16x16x32_bf16(a1, bb0, acc[1][0], 0, 0, 0);
        acc[1][1] = __builtin_amdgcn_mfma_f32_16x16x32_bf16(a1, bb1, acc[1][1], 0, 0, 0);
    }

    #pragma unroll
    for (int mi = 0; mi < 2; ++mi) {
        int cb = wv*32 + mi*16 + quad*4;
        float g0 = b1[cb], g1 = b1[cb+1], g2 = b1[cb+2], g3 = b1[cb+3];
        #pragma unroll
        for (int ni = 0; ni < 2; ++ni) {
            short4v s = { f2bf(elu_f(acc[mi][ni][0] + g0)),
                          f2bf(elu_f(acc[mi][ni][1] + g1)),
                          f2bf(elu_f(acc[mi][ni][2] + g2)),
                          f2bf(elu_f(acc[mi][ni][3] + g3)) };
            *(short4v*)&t1[(ni*16 + l15)*TST + cb] = s;
        }
    }
    __syncthreads();

    floatx4 acc2[2][2] = {{{0,0,0,0},{0,0,0,0}},{{0,0,0,0},{0,0,0,0}}};

    #pragma unroll
    for (int ks = 0; ks < 4; ++ks) {
        int koff = ks*32 + quad*8;
        short8 a0 = *(const short8*)&w2T[(size_t)(wv*32 + l15)*128 + koff];
        short8 a1 = *(const short8*)&w2T[(size_t)(wv*32 + 16 + l15)*128 + koff];
        short8 bb0 = *(const short8*)&t1[l15*TST + koff];
        short8 bb1 = *(const short8*)&t1[(16 + l15)*TST + koff];
        acc2[0][0] = __builtin_amdgcn_mfma_f32_16x16x32_bf16(a0, bb0, acc2[0][0], 0, 0, 0);
        acc2[0][1] = __builtin_amdgcn_mfma_f32_16x16x32_bf16(a0, bb1, acc2[0][1], 0, 0, 0);
        acc2[1][0] = __builtin_amdgcn_mfma_f32_16x16x32_bf16(a1, bb0, acc2[1][0], 0, 0, 0);
        acc2[1][1] = __builtin_amdgcn_mfma_f32_16x16x32_bf16(a1, bb1, acc2[1][1], 0, 0, 0);
    }

    #pragma unroll
    for (int mi = 0; mi < 2; ++mi) {
        int cb = wv*32 + mi*16 + quad*4;
        float g0 = b2[cb], g1 = b2[cb+1], g2 = b2[cb+2], g3 = b2[cb+3];
        #pragma unroll
        for (int ni = 0; ni < 2; ++ni) {
            int n = n0 + ni*16 + l15;
            if (n < N_NODES) {
                short4v s = { f2bf(acc2[mi][ni][0] + g0), f2bf(acc2[mi][ni][1] + g1),
                              f2bf(acc2[mi][ni][2] + g2), f2bf(acc2[mi][ni][3] + g3) };
                *(short4v*)&hout_bf[(size_t)n*HID + cb] = s;
            }
        }
    }
}

// ---------------- output head: z = mu + 0.01*eps*exp(0.5*logvar), bf16 h ----------------
__global__ void out_kernel(const short* __restrict__ h_bf, const float* __restrict__ label,
                           const float* __restrict__ eps,
                           const float* __restrict__ mu_w, const float* __restrict__ mu_b,
                           const float* __restrict__ var_w, const float* __restrict__ var_b,
                           float* __restrict__ z)
{
    int t = threadIdx.x;
    int n = blockIdx.x * 4 + (t >> 6);
    int c = t & 63;
    if (n >= N_NODES) return;
    float am = mu_b[c], av = var_b[c];
    #pragma unroll 4
    for (int k = 0; k < HID; ++k) {
        float hv = bf2f(h_bf[(size_t)n*HID + k]);
        am += hv * mu_w[k*LAT + c];
        av += hv * var_w[k*LAT + c];
    }
    #pragma unroll
    for (int k = 0; k < 7; ++k) {
        float lv = label[(size_t)n*7 + k];
        am += lv * mu_w[(HID+k)*LAT + c];
        av += lv * var_w[(HID+k)*LAT + c];
    }
    float sd = expf(av * 0.5f);
    z[(size_t)n*LAT + c] = am + 0.01f * eps[(size_t)n*LAT + c] * sd;
}

extern "C" void kernel_launch(void* const* d_in, const int* in_sizes, int n_in,
                              void* d_out, int out_size, void* d_ws, size_t ws_size,
                              hipStream_t stream) {
    const float* h0        = (const float*)d_in[0];
    const float* label     = (const float*)d_in[1];
    const float* x         = (const float*)d_in[2];
    const float* edge_attr = (const float*)d_in[3];
    const float* eps       = (const float*)d_in[4];
    const float* emb_w     = (const float*)d_in[5];
    const float* emb_b     = (const float*)d_in[6];
    const float* edge_w1   = (const float*)d_in[7];
    const float* edge_b1   = (const float*)d_in[8];
    const float* edge_w2   = (const float*)d_in[9];
    const float* edge_b2   = (const float*)d_in[10];
    const float* node_w1   = (const float*)d_in[11];
    const float* node_b1   = (const float*)d_in[12];
    const float* node_w2   = (const float*)d_in[13];
    const float* node_b2   = (const float*)d_in[14];
    const float* mu_w      = (const float*)d_in[15];
    const float* mu_b      = (const float*)d_in[16];
    const float* var_w     = (const float*)d_in[17];
    const float* var_b     = (const float*)d_in[18];
    const int*   edges     = (const int*)d_in[19];
    float* out = (float*)d_out;

    float* agg      = (float*)d_ws;                     // N*128 f32
    short* h_bf     = (short*)(agg + (size_t)N_NODES * HID);  // N*128 bf16
    short* tail_u   = h_bf + (size_t)N_NODES * HID;     // E*8 bf16 (unsorted)
    short* tail_s   = tail_u + (size_t)N_EDGES * 8;     // E*8 bf16 (sorted)
    int*   cnt      = (int*)(tail_s + (size_t)N_EDGES * 8);   // N int
    int*   cursor   = cnt + N_NODES;                    // N int
    int*   srow     = cursor + N_NODES;                 // E int
    int*   scol     = srow + N_EDGES;                   // E int
    short* ew1T     = (short*)(scol + N_EDGES);         // 2*128*288
    short* ew2T     = ew1T + 2*128*KP1;                 // 2*128*128
    short* nw1T     = ew2T + 2*128*128;                 // 2*128*256
    short* nw2T     = nw1T + 2*128*KN;                  // 2*128*128

    // CSR build (once per launch, reused by both layers)
    hipMemsetAsync(cnt, 0, N_NODES * sizeof(int), stream);
    csr_count_tail<<<(N_EDGES + 255) / 256, 256, 0, stream>>>(edges, x, edge_attr,
                                                              cnt, tail_u);
    csr_prefix<<<1, 256, 0, stream>>>(cnt, cursor);
    csr_place<<<(N_EDGES + 255) / 256, 256, 0, stream>>>(edges, tail_u, cursor,
                                                         srow, scol, tail_s);

    prep_weights<<<200, 256, 0, stream>>>(edge_w1, edge_w2, node_w1, node_w2,
                                          ew1T, ew2T, nw1T, nw2T);
    emb_kernel<<<N_NODES / 2, 256, 0, stream>>>(h0, emb_w, emb_b, h_bf);

    for (int l = 0; l < 2; ++l) {
        hipMemsetAsync(agg, 0, (size_t)N_NODES * HID * sizeof(float), stream);
        edge_mfma_kernel<<<N_EDGES / 32 / NTPB, 256, 0, stream>>>(
            h_bf, tail_s, srow, scol,
            ew1T + (size_t)l * 128 * KP1, edge_b1 + l * HID,
            ew2T + (size_t)l * 128 * 128, edge_b2 + l * HID, agg);
        node_mfma_kernel<<<(N_NODES + 31) / 32, 256, 0, stream>>>(
            h_bf, agg,
            nw1T + (size_t)l * 128 * KN, node_b1 + l * HID,
            nw2T + (size_t)l * 128 * 128, node_b2 + l * HID, h_bf);
    }

    out_kernel<<<N_NODES / 4, 256, 0, stream>>>(h_bf, label, eps, mu_w, mu_b,
                                                var_w, var_b, out);
}

// Round 7
// 845.929 us; speedup vs baseline: 3.6296x; 1.0199x over previous
//
#include <hip/hip_runtime.h>
#include <math.h>

#define N_NODES 50000
#define N_EDGES 800000
#define HID 128
#define LAT 64
#define IN_NODE 11
#define K_EDGE 261    // 2*HID + 1 + 4
#define KP1 288       // K_EDGE padded to multiple of 32
#define KN 256        // node MLP folded K (h + agg)
#define AST 296       // edge feature LDS row stride (bf16 elems), 288+8 pad
#define NST 264       // node feature LDS row stride, 256+8 pad
#define TST 136       // t1 LDS row stride, 128+8 pad
#define MST 132       // msg LDS row stride (floats), 128+4 pad
#define PCHUNK 196    // prefix-scan chunk: 256*196 >= 50000
#define NTPB 20       // edge tiles per block (grid 1250)
#define NTN 4         // node tiles per block (grid 391)

typedef __attribute__((ext_vector_type(8))) short short8;
typedef __attribute__((ext_vector_type(4))) short short4v;
typedef __attribute__((ext_vector_type(4))) float floatx4;

__device__ __forceinline__ float elu_f(float v) { return v > 0.0f ? v : __expf(v) - 1.0f; }

__device__ __forceinline__ short f2bf(float f) {
    unsigned int u = __builtin_bit_cast(unsigned int, f);
    u += 0x7fffu + ((u >> 16) & 1u);   // round-to-nearest-even
    return (short)(u >> 16);
}

__device__ __forceinline__ float bf2f(short s) {
    unsigned int u = ((unsigned int)(unsigned short)s) << 16;
    return __builtin_bit_cast(float, u);
}

// ---------------- CSR pass 1: count + radial + bf16 tail pack (coalesced) ----------------
__global__ void csr_count_tail(const int* __restrict__ edges, const float* __restrict__ x,
                               const float* __restrict__ edge_attr,
                               int* __restrict__ cnt, short* __restrict__ tail_u) {
    int e = blockIdx.x * 256 + threadIdx.x;
    if (e >= N_EDGES) return;
    int r = edges[e], c = edges[N_EDGES + e];
    atomicAdd(&cnt[r], 1);
    float dx = x[r*3+0] - x[c*3+0];
    float dy = x[r*3+1] - x[c*3+1];
    float dz = x[r*3+2] - x[c*3+2];
    float radial = dx*dx + dy*dy + dz*dz;
    float4 ea = *(const float4*)(edge_attr + (size_t)e * 4);
    short8 s = { f2bf(radial), f2bf(ea.x), f2bf(ea.y), f2bf(ea.z), f2bf(ea.w), 0, 0, 0 };
    *(short8*)(tail_u + (size_t)e * 8) = s;
}

// ---------------- CSR pass 2: prefix over per-row counts ----------------
__global__ void csr_prefix(const int* __restrict__ cnt, int* __restrict__ cursor) {
    __shared__ int tot[256];
    __shared__ int pre[256];
    int t = threadIdx.x;
    int lo = t * PCHUNK, hi = lo + PCHUNK; if (hi > N_NODES) hi = N_NODES;
    int s = 0;
    for (int i = lo; i < hi; ++i) s += cnt[i];
    tot[t] = s;
    __syncthreads();
    if (t == 0) {
        int acc = 0;
        for (int i = 0; i < 256; ++i) { pre[i] = acc; acc += tot[i]; }
    }
    __syncthreads();
    int acc = pre[t];
    for (int i = lo; i < hi; ++i) { cursor[i] = acc; acc += cnt[i]; }
}

// ---------------- CSR pass 3: place srow/scol/tail in sorted order ----------------
__global__ void csr_place(const int* __restrict__ edges, const short* __restrict__ tail_u,
                          int* __restrict__ cursor, int* __restrict__ srow,
                          int* __restrict__ scol, short* __restrict__ tail_s) {
    int e = blockIdx.x * 256 + threadIdx.x;
    if (e >= N_EDGES) return;
    int r = edges[e], c = edges[N_EDGES + e];
    short8 s = *(const short8*)(tail_u + (size_t)e * 8);
    int pos = atomicAdd(&cursor[r], 1);
    srow[pos] = r; scol[pos] = c;
    *(short8*)(tail_s + (size_t)pos * 8) = s;
}

// ---------------- embedding: h_bf = bf16(h0 @ emb_w + emb_b) ----------------
__global__ void emb_kernel(const float* __restrict__ h0, const float* __restrict__ w,
                           const float* __restrict__ b, short* __restrict__ h_bf) {
    int t = threadIdx.x;
    int n = blockIdx.x * 2 + (t >> 7);
    int c = t & 127;
    if (n >= N_NODES) return;
    float acc = b[c];
    #pragma unroll
    for (int k = 0; k < IN_NODE; ++k) acc += h0[n*IN_NODE + k] * w[k*HID + c];
    h_bf[(size_t)n*HID + c] = f2bf(acc);
}

// ---------------- weight prep: transpose + bf16 + pad/fold ----------------
__global__ void prep_weights(const float* __restrict__ ew1, const float* __restrict__ ew2,
                             const float* __restrict__ nw1, const float* __restrict__ nw2,
                             short* __restrict__ ew1T, short* __restrict__ ew2T,
                             short* __restrict__ nw1T, short* __restrict__ nw2T) {
    int idx = blockIdx.x * 256 + threadIdx.x;
    int stride = gridDim.x * 256;
    for (int i = idx; i < 2*128*KP1; i += stride) {
        int l = i / (128*KP1); int r = i % (128*KP1);
        int c = r / KP1; int k = r % KP1;
        float v = (k < K_EDGE) ? ew1[(size_t)l*K_EDGE*128 + (size_t)k*128 + c] : 0.0f;
        ew1T[i] = f2bf(v);
    }
    for (int i = idx; i < 2*128*128; i += stride) {
        int l = i / (128*128); int r = i % (128*128);
        int c = r / 128; int k = r % 128;
        ew2T[i] = f2bf(ew2[(size_t)l*128*128 + (size_t)k*128 + c]);
    }
    for (int i = idx; i < 2*128*KN; i += stride) {
        int l = i / (128*KN); int r = i % (128*KN);
        int c = r / KN; int k = r % KN;
        const float* base = nw1 + (size_t)l*384*128;
        float v = (k < 128) ? (base[(size_t)k*128 + c] + base[(size_t)(256+k)*128 + c])
                            : base[(size_t)k*128 + c];
        nw1T[i] = f2bf(v);
    }
    for (int i = idx; i < 2*128*128; i += stride) {
        int l = i / (128*128); int r = i % (128*128);
        int c = r / 128; int k = r % 128;
        nw2T[i] = f2bf(nw2[(size_t)l*128*128 + (size_t)k*128 + c]);
    }
}

// ---------------- MFMA edge MLP: register weights, NTPB tiles/block, msg overlaid ----------------
__global__ __launch_bounds__(256, 2) void edge_mfma_kernel(
    const short* __restrict__ h_bf, const short* __restrict__ tail_s,
    const int* __restrict__ srow, const int* __restrict__ scol,
    const short* __restrict__ w1T, const float* __restrict__ b1,
    const short* __restrict__ w2T, const float* __restrict__ b2,
    float* __restrict__ agg)
{
    __shared__ __align__(16) short featA[32 * AST];   // 18944 B; msg overlays here
    __shared__ __align__(16) short t1[32 * TST];      // 8704 B
    __shared__ int srowS[32];
    float* msgF = (float*)featA;                      // 32 x MST floats = 16896 B <= featA
    int t = threadIdx.x;
    int lane = t & 63;
    int wv = t >> 6;          // wave: channel block [wv*32, wv*32+32)
    int l15 = lane & 15;
    int quad = lane >> 4;
    int el = t >> 3, j = t & 7;

    // ---- preload this wave's weight fragments into registers (once) ----
    short8 aw1[2][9], aw2[2][4];
    float4 b1v[2], b2v[2];
    #pragma unroll
    for (int mi = 0; mi < 2; ++mi) {
        #pragma unroll
        for (int ks = 0; ks < 9; ++ks)
            aw1[mi][ks] = *(const short8*)&w1T[(size_t)(wv*32 + mi*16 + l15)*KP1 + ks*32 + quad*8];
        #pragma unroll
        for (int ks = 0; ks < 4; ++ks)
            aw2[mi][ks] = *(const short8*)&w2T[(size_t)(wv*32 + mi*16 + l15)*128 + ks*32 + quad*8];
        b1v[mi] = *(const float4*)&b1[wv*32 + mi*16 + quad*4];
        b2v[mi] = *(const float4*)&b2[wv*32 + mi*16 + quad*4];
    }

    for (int it = 0; it < NTPB; ++it) {
        int e0 = (blockIdx.x * NTPB + it) * 32;
        __syncthreads();   // prior iteration's msg reads done before featA overwrite

        // ---- stage 32 edges' gathered bf16 features ----
        {
            int e = e0 + el;
            int r = srow[e], c = scol[e];
            if (j == 0) srowS[el] = r;
            const short8* hr = (const short8*)(h_bf + (size_t)r * HID + j*16);
            const short8* hc = (const short8*)(h_bf + (size_t)c * HID + j*16);
            short8 s0 = hr[0], s1 = hr[1];
            short8 s2 = hc[0], s3 = hc[1];
            *(short8*)&featA[el*AST + j*16]       = s0;
            *(short8*)&featA[el*AST + j*16 + 8]   = s1;
            *(short8*)&featA[el*AST + 128 + j*16]     = s2;
            *(short8*)&featA[el*AST + 128 + j*16 + 8] = s3;
        }
        if (t < 32) {
            int e = e0 + t;
            short8 s = *(const short8*)(tail_s + (size_t)e * 8);
            short8 z = {0,0,0,0,0,0,0,0};
            *(short8*)&featA[t*AST + 256] = s;
            *(short8*)&featA[t*AST + 264] = z;
            *(short8*)&featA[t*AST + 272] = z;
            *(short8*)&featA[t*AST + 280] = z;
        }
        __syncthreads();

        // ---- layer 1: K = 288, A resident ----
        floatx4 acc[2][2] = {{{0,0,0,0},{0,0,0,0}},{{0,0,0,0},{0,0,0,0}}};
        #pragma unroll
        for (int ks = 0; ks < 9; ++ks) {
            int koff = ks*32 + quad*8;
            short8 bb0 = *(const short8*)&featA[l15*AST + koff];
            short8 bb1 = *(const short8*)&featA[(16 + l15)*AST + koff];
            acc[0][0] = __builtin_amdgcn_mfma_f32_16x16x32_bf16(aw1[0][ks], bb0, acc[0][0], 0, 0, 0);
            acc[0][1] = __builtin_amdgcn_mfma_f32_16x16x32_bf16(aw1[0][ks], bb1, acc[0][1], 0, 0, 0);
            acc[1][0] = __builtin_amdgcn_mfma_f32_16x16x32_bf16(aw1[1][ks], bb0, acc[1][0], 0, 0, 0);
            acc[1][1] = __builtin_amdgcn_mfma_f32_16x16x32_bf16(aw1[1][ks], bb1, acc[1][1], 0, 0, 0);
        }

        // ---- epilogue 1: bias + elu -> bf16 t1[e][c] ----
        #pragma unroll
        for (int mi = 0; mi < 2; ++mi) {
            int cb = wv*32 + mi*16 + quad*4;
            #pragma unroll
            for (int ni = 0; ni < 2; ++ni) {
                short4v s = { f2bf(elu_f(acc[mi][ni][0] + b1v[mi].x)),
                              f2bf(elu_f(acc[mi][ni][1] + b1v[mi].y)),
                              f2bf(elu_f(acc[mi][ni][2] + b1v[mi].z)),
                              f2bf(elu_f(acc[mi][ni][3] + b1v[mi].w)) };
                *(short4v*)&t1[(ni*16 + l15)*TST + cb] = s;
            }
        }
        __syncthreads();   // featA reads done (L1 K-loop) -> msg overlay safe after here

        // ---- layer 2: K = 128, A resident ----
        floatx4 acc2[2][2] = {{{0,0,0,0},{0,0,0,0}},{{0,0,0,0},{0,0,0,0}}};
        #pragma unroll
        for (int ks = 0; ks < 4; ++ks) {
            int koff = ks*32 + quad*8;
            short8 bb0 = *(const short8*)&t1[l15*TST + koff];
            short8 bb1 = *(const short8*)&t1[(16 + l15)*TST + koff];
            acc2[0][0] = __builtin_amdgcn_mfma_f32_16x16x32_bf16(aw2[0][ks], bb0, acc2[0][0], 0, 0, 0);
            acc2[0][1] = __builtin_amdgcn_mfma_f32_16x16x32_bf16(aw2[0][ks], bb1, acc2[0][1], 0, 0, 0);
            acc2[1][0] = __builtin_amdgcn_mfma_f32_16x16x32_bf16(aw2[1][ks], bb0, acc2[1][0], 0, 0, 0);
            acc2[1][1] = __builtin_amdgcn_mfma_f32_16x16x32_bf16(aw2[1][ks], bb1, acc2[1][1], 0, 0, 0);
        }

        // ---- epilogue 2: bias + elu -> f32 msg tile (overlaid on featA) ----
        #pragma unroll
        for (int mi = 0; mi < 2; ++mi) {
            int cb = wv*32 + mi*16 + quad*4;
            #pragma unroll
            for (int ni = 0; ni < 2; ++ni) {
                float4 v = { elu_f(acc2[mi][ni][0] + b2v[mi].x), elu_f(acc2[mi][ni][1] + b2v[mi].y),
                             elu_f(acc2[mi][ni][2] + b2v[mi].z), elu_f(acc2[mi][ni][3] + b2v[mi].w) };
                *(float4*)&msgF[(ni*16 + l15)*MST + cb] = v;
            }
        }
        __syncthreads();

        // ---- segmented reduce: thread (c, half) walks 16 sorted edges, flush per run ----
        {
            int c = t & 127, half = t >> 7;
            int base = half * 16;
            int prow = srowS[base];
            float run = 0.0f;
            #pragma unroll
            for (int i = 0; i < 16; ++i) {
                int rr = srowS[base + i];
                if (rr != prow) {
                    unsafeAtomicAdd(&agg[(size_t)prow * HID + c], run);
                    run = 0.0f; prow = rr;
                }
                run += msgF[(base + i)*MST + c];
            }
            unsafeAtomicAdd(&agg[(size_t)prow * HID + c], run);
        }
    }
}

// ---------------- MFMA node MLP: register weights, NTN tiles/block ----------------
__global__ __launch_bounds__(256) void node_mfma_kernel(
    const short* __restrict__ h_bf, const float* __restrict__ agg,
    const short* __restrict__ w1T, const float* __restrict__ b1,
    const short* __restrict__ w2T, const float* __restrict__ b2,
    short* __restrict__ hout_bf)
{
    __shared__ short featN[32 * NST];   // 16896 B
    __shared__ short t1[32 * TST];      // 8704 B
    int t = threadIdx.x;
    int lane = t & 63;
    int wv = t >> 6;
    int l15 = lane & 15;
    int quad = lane >> 4;
    int nl = t >> 3, j = t & 7;

    // ---- preload this wave's weight fragments (once) ----
    short8 aw1[2][8], aw2[2][4];
    float4 b1v[2], b2v[2];
    #pragma unroll
    for (int mi = 0; mi < 2; ++mi) {
        #pragma unroll
        for (int ks = 0; ks < 8; ++ks)
            aw1[mi][ks] = *(const short8*)&w1T[(size_t)(wv*32 + mi*16 + l15)*KN + ks*32 + quad*8];
        #pragma unroll
        for (int ks = 0; ks < 4; ++ks)
            aw2[mi][ks] = *(const short8*)&w2T[(size_t)(wv*32 + mi*16 + l15)*128 + ks*32 + quad*8];
        b1v[mi] = *(const float4*)&b1[wv*32 + mi*16 + quad*4];
        b2v[mi] = *(const float4*)&b2[wv*32 + mi*16 + quad*4];
    }

    for (int it = 0; it < NTN; ++it) {
        int n0 = (blockIdx.x * NTN + it) * 32;
        if (n0 >= N_NODES) break;          // block-uniform
        __syncthreads();

        {
            int n = n0 + nl;
            int idx = n < N_NODES ? n : N_NODES - 1;
            const short8* hp = (const short8*)(h_bf + (size_t)idx * HID + j*16);
            short8 s0 = hp[0], s1 = hp[1];
            const float4* ap = (const float4*)(agg + (size_t)idx * HID) + j*4;
            float4 u0 = ap[0], u1 = ap[1], u2 = ap[2], u3 = ap[3];
            short8 s2 = { f2bf(u0.x), f2bf(u0.y), f2bf(u0.z), f2bf(u0.w),
                          f2bf(u1.x), f2bf(u1.y), f2bf(u1.z), f2bf(u1.w) };
            short8 s3 = { f2bf(u2.x), f2bf(u2.y), f2bf(u2.z), f2bf(u2.w),
                          f2bf(u3.x), f2bf(u3.y), f2bf(u3.z), f2bf(u3.w) };
            *(short8*)&featN[nl*NST + j*16]       = s0;
            *(short8*)&featN[nl*NST + j*16 + 8]   = s1;
            *(short8*)&featN[nl*NST + 128 + j*16]     = s2;
            *(short8*)&featN[nl*NST + 128 + j*16 + 8] = s3;
        }
        __syncthreads();

        floatx4 acc[2][2] = {{{0,0,0,0},{0,0,0,0}},{{0,0,0,0},{0,0,0,0}}};
        #pragma unroll
        for (int ks = 0; ks < 8; ++ks) {
            int koff = ks*32 + quad*8;
            short8 bb0 = *(const short8*)&featN[l15*NST + koff];
            short8 bb1 = *(const short8*)&featN[(16 + l15)*NST + koff];
            acc[0][0] = __builtin_amdgcn_mfma_f32_16x16x32_bf16(aw1[0][ks], bb0, acc[0][0], 0, 0, 0);
            acc[0][1] = __builtin_amdgcn_mfma_f32_16x16x32_bf16(aw1[0][ks], bb1, acc[0][1], 0, 0, 0);
            acc[1][0] = __builtin_amdgcn_mfma_f32_16x16x32_bf16(aw1[1][ks], bb0, acc[1][0], 0, 0, 0);
            acc[1][1] = __builtin_amdgcn_mfma_f32_16x16x32_bf16(aw1[1][ks], bb1, acc[1][1], 0, 0, 0);
        }

        #pragma unroll
        for (int mi = 0; mi < 2; ++mi) {
            int cb = wv*32 + mi*16 + quad*4;
            #pragma unroll
            for (int ni = 0; ni < 2; ++ni) {
                short4v s = { f2bf(elu_f(acc[mi][ni][0] + b1v[mi].x)),
                              f2bf(elu_f(acc[mi][ni][1] + b1v[mi].y)),
                              f2bf(elu_f(acc[mi][ni][2] + b1v[mi].z)),
                              f2bf(elu_f(acc[mi][ni][3] + b1v[mi].w)) };
                *(short4v*)&t1[(ni*16 + l15)*TST + cb] = s;
            }
        }
        __syncthreads();

        floatx4 acc2[2][2] = {{{0,0,0,0},{0,0,0,0}},{{0,0,0,0},{0,0,0,0}}};
        #pragma unroll
        for (int ks = 0; ks < 4; ++ks) {
            int koff = ks*32 + quad*8;
            short8 bb0 = *(const short8*)&t1[l15*TST + koff];
            short8 bb1 = *(const short8*)&t1[(16 + l15)*TST + koff];
            acc2[0][0] = __builtin_amdgcn_mfma_f32_16x16x32_bf16(aw2[0][ks], bb0, acc2[0][0], 0, 0, 0);
            acc2[0][1] = __builtin_amdgcn_mfma_f32_16x16x32_bf16(aw2[0][ks], bb1, acc2[0][1], 0, 0, 0);
            acc2[1][0] = __builtin_amdgcn_mfma_f32_16x16x32_bf16(aw2[1][ks], bb0, acc2[1][0], 0, 0, 0);
            acc2[1][1] = __builtin_amdgcn_mfma_f32_16x16x32_bf16(aw2[1][ks], bb1, acc2[1][1], 0, 0, 0);
        }

        #pragma unroll
        for (int mi = 0; mi < 2; ++mi) {
            int cb = wv*32 + mi*16 + quad*4;
            #pragma unroll
            for (int ni = 0; ni < 2; ++ni) {
                int n = n0 + ni*16 + l15;
                if (n < N_NODES) {
                    short4v s = { f2bf(acc2[mi][ni][0] + b2v[mi].x), f2bf(acc2[mi][ni][1] + b2v[mi].y),
                                  f2bf(acc2[mi][ni][2] + b2v[mi].z), f2bf(acc2[mi][ni][3] + b2v[mi].w) };
                    *(short4v*)&hout_bf[(size_t)n*HID + cb] = s;
                }
            }
        }
    }
}

// ---------------- output head: z = mu + 0.01*eps*exp(0.5*logvar), bf16 h ----------------
__global__ void out_kernel(const short* __restrict__ h_bf, const float* __restrict__ label,
                           const float* __restrict__ eps,
                           const float* __restrict__ mu_w, const float* __restrict__ mu_b,
                           const float* __restrict__ var_w, const float* __restrict__ var_b,
                           float* __restrict__ z)
{
    int t = threadIdx.x;
    int n = blockIdx.x * 4 + (t >> 6);
    int c = t & 63;
    if (n >= N_NODES) return;
    float am = mu_b[c], av = var_b[c];
    #pragma unroll 4
    for (int k = 0; k < HID; ++k) {
        float hv = bf2f(h_bf[(size_t)n*HID + k]);
        am += hv * mu_w[k*LAT + c];
        av += hv * var_w[k*LAT + c];
    }
    #pragma unroll
    for (int k = 0; k < 7; ++k) {
        float lv = label[(size_t)n*7 + k];
        am += lv * mu_w[(HID+k)*LAT + c];
        av += lv * var_w[(HID+k)*LAT + c];
    }
    float sd = expf(av * 0.5f);
    z[(size_t)n*LAT + c] = am + 0.01f * eps[(size_t)n*LAT + c] * sd;
}

extern "C" void kernel_launch(void* const* d_in, const int* in_sizes, int n_in,
                              void* d_out, int out_size, void* d_ws, size_t ws_size,
                              hipStream_t stream) {
    const float* h0        = (const float*)d_in[0];
    const float* label     = (const float*)d_in[1];
    const float* x         = (const float*)d_in[2];
    const float* edge_attr = (const float*)d_in[3];
    const float* eps       = (const float*)d_in[4];
    const float* emb_w     = (const float*)d_in[5];
    const float* emb_b     = (const float*)d_in[6];
    const float* edge_w1   = (const float*)d_in[7];
    const float* edge_b1   = (const float*)d_in[8];
    const float* edge_w2   = (const float*)d_in[9];
    const float* edge_b2   = (const float*)d_in[10];
    const float* node_w1   = (const float*)d_in[11];
    const float* node_b1   = (const float*)d_in[12];
    const float* node_w2   = (const float*)d_in[13];
    const float* node_b2   = (const float*)d_in[14];
    const float* mu_w      = (const float*)d_in[15];
    const float* mu_b      = (const float*)d_in[16];
    const float* var_w     = (const float*)d_in[17];
    const float* var_b     = (const float*)d_in[18];
    const int*   edges     = (const int*)d_in[19];
    float* out = (float*)d_out;

    float* agg      = (float*)d_ws;                     // N*128 f32
    short* h_bf     = (short*)(agg + (size_t)N_NODES * HID);  // N*128 bf16
    short* tail_u   = h_bf + (size_t)N_NODES * HID;     // E*8 bf16 (unsorted)
    short* tail_s   = tail_u + (size_t)N_EDGES * 8;     // E*8 bf16 (sorted)
    int*   cnt      = (int*)(tail_s + (size_t)N_EDGES * 8);   // N int
    int*   cursor   = cnt + N_NODES;                    // N int
    int*   srow     = cursor + N_NODES;                 // E int
    int*   scol     = srow + N_EDGES;                   // E int
    short* ew1T     = (short*)(scol + N_EDGES);         // 2*128*288
    short* ew2T     = ew1T + 2*128*KP1;                 // 2*128*128
    short* nw1T     = ew2T + 2*128*128;                 // 2*128*256
    short* nw2T     = nw1T + 2*128*KN;                  // 2*128*128

    // CSR build (once per launch, reused by both layers)
    hipMemsetAsync(cnt, 0, N_NODES * sizeof(int), stream);
    csr_count_tail<<<(N_EDGES + 255) / 256, 256, 0, stream>>>(edges, x, edge_attr,
                                                              cnt, tail_u);
    csr_prefix<<<1, 256, 0, stream>>>(cnt, cursor);
    csr_place<<<(N_EDGES + 255) / 256, 256, 0, stream>>>(edges, tail_u, cursor,
                                                         srow, scol, tail_s);

    prep_weights<<<200, 256, 0, stream>>>(edge_w1, edge_w2, node_w1, node_w2,
                                          ew1T, ew2T, nw1T, nw2T);
    emb_kernel<<<N_NODES / 2, 256, 0, stream>>>(h0, emb_w, emb_b, h_bf);

    for (int l = 0; l < 2; ++l) {
        hipMemsetAsync(agg, 0, (size_t)N_NODES * HID * sizeof(float), stream);
        edge_mfma_kernel<<<N_EDGES / 32 / NTPB, 256, 0, stream>>>(
            h_bf, tail_s, srow, scol,
            ew1T + (size_t)l * 128 * KP1, edge_b1 + l * HID,
            ew2T + (size_t)l * 128 * 128, edge_b2 + l * HID, agg);
        node_mfma_kernel<<<(N_NODES/32 + NTN) / NTN, 256, 0, stream>>>(
            h_bf, agg,
            nw1T + (size_t)l * 128 * KN, node_b1 + l * HID,
            nw2T + (size_t)l * 128 * 128, node_b2 + l * HID, h_bf);
    }

    out_kernel<<<N_NODES / 4, 256, 0, stream>>>(h_bf, label, eps, mu_w, mu_b,
                                                var_w, var_b, out);
}